// Round 1
// baseline (1819.717 us; speedup 1.0000x reference)
//
#include <hip/hip_runtime.h>
#include <hip/hip_bf16.h>

typedef __hip_bfloat16 bf16;

constexpr int B_     = 16;
constexpr int C_     = 256;   // DIM
constexpr int INNER_ = 512;
constexpr int HEADS_ = 8;
constexpr int DH_    = 64;
constexpr int HW_    = 56;
constexpr int NPIX_  = HW_ * HW_;   // 3136
constexpr int WS_    = 7;
constexpr int WSQ_   = 49;
constexpr int NWIN_  = 64;          // 8x8 windows

static __device__ __forceinline__ float u16tof(unsigned short u) {
    return __uint_as_float(((unsigned int)u) << 16);
}

// ---------------------------------------------------------------------------
// Kernel 1: depthwise 3x3 conv (pad 1) + BN(eval) -> bf16 t [B,256,56,56]
// ---------------------------------------------------------------------------
__global__ __launch_bounds__(256) void dwbn_kernel(
    const float* __restrict__ x, const float* __restrict__ dw,
    const float* __restrict__ g, const float* __restrict__ bb,
    const float* __restrict__ mm, const float* __restrict__ vv,
    bf16* __restrict__ t) {
    int idx = blockIdx.x * 256 + threadIdx.x;          // B*C*NPIX threads
    int p = idx % NPIX_;
    int c = (idx / NPIX_) % C_;
    int b = idx / (NPIX_ * C_);
    int y = p / HW_, xx = p % HW_;
    const float* xp = x + (size_t)(b * C_ + c) * NPIX_;
    const float* w9 = dw + c * 9;
    float acc = 0.f;
#pragma unroll
    for (int ky = 0; ky < 3; ++ky) {
        int yy = y + ky - 1;
        if (yy < 0 || yy >= HW_) continue;
#pragma unroll
        for (int kx = 0; kx < 3; ++kx) {
            int xc = xx + kx - 1;
            if (xc < 0 || xc >= HW_) continue;
            acc += w9[ky * 3 + kx] * xp[yy * HW_ + xc];
        }
    }
    float scale = g[c] * rsqrtf(vv[c] + 1e-5f);
    float r = (acc - mm[c]) * scale + bb[c];
    t[idx] = __float2bfloat16(r);
}

// ---------------------------------------------------------------------------
// Kernel 2: pointwise GEMM  C[m][n] = sum_k A[m][k] * B[k][n]
//   A: fp32 [M x K] (pointwise weights), B: bf16 [K x NPIX] per batch (t)
//   Epilogue: write into windowed layout Q[b][head][win][j49][d] (bf16)
// blockDim 256, tile 64x64, K-tile 16, thread micro-tile 4x4.
// ---------------------------------------------------------------------------
__global__ __launch_bounds__(256) void gemm_qkv_kernel(
    const float* __restrict__ A, const bf16* __restrict__ Bm,
    bf16* __restrict__ Q, int K) {
    __shared__ float sA[16][65];
    __shared__ float sB[16][65];
    int tid = threadIdx.x;
    int m0 = blockIdx.x * 64;
    int n0 = blockIdx.y * 64;
    int b  = blockIdx.z;
    const bf16* Bp = Bm + (size_t)b * K * NPIX_;
    float acc[4][4] = {};
    int tm = (tid / 16) * 4;
    int tn = (tid % 16) * 4;
    for (int k0 = 0; k0 < K; k0 += 16) {
        {   // A tile: 64 rows (m) x 16 cols (k)
            int mi = tid >> 2;
            int kb = (tid & 3) * 4;
            float4 av = *(const float4*)(A + (size_t)(m0 + mi) * K + k0 + kb);
            sA[kb + 0][mi] = av.x; sA[kb + 1][mi] = av.y;
            sA[kb + 2][mi] = av.z; sA[kb + 3][mi] = av.w;
        }
        {   // B tile: 16 rows (k) x 64 cols (n)
            int kk = tid >> 4;
            int nb = (tid & 15) * 4;
            ushort4 bv = *(const ushort4*)(Bp + (size_t)(k0 + kk) * NPIX_ + n0 + nb);
            sB[kk][nb + 0] = u16tof(bv.x); sB[kk][nb + 1] = u16tof(bv.y);
            sB[kk][nb + 2] = u16tof(bv.z); sB[kk][nb + 3] = u16tof(bv.w);
        }
        __syncthreads();
#pragma unroll
        for (int kk = 0; kk < 16; ++kk) {
            float a0 = sA[kk][tm + 0], a1 = sA[kk][tm + 1];
            float a2 = sA[kk][tm + 2], a3 = sA[kk][tm + 3];
            float b0 = sB[kk][tn + 0], b1 = sB[kk][tn + 1];
            float b2 = sB[kk][tn + 2], b3 = sB[kk][tn + 3];
            acc[0][0] += a0 * b0; acc[0][1] += a0 * b1; acc[0][2] += a0 * b2; acc[0][3] += a0 * b3;
            acc[1][0] += a1 * b0; acc[1][1] += a1 * b1; acc[1][2] += a1 * b2; acc[1][3] += a1 * b3;
            acc[2][0] += a2 * b0; acc[2][1] += a2 * b1; acc[2][2] += a2 * b2; acc[2][3] += a2 * b3;
            acc[3][0] += a3 * b0; acc[3][1] += a3 * b1; acc[3][2] += a3 * b2; acc[3][3] += a3 * b3;
        }
        __syncthreads();
    }
#pragma unroll
    for (int i = 0; i < 4; ++i) {
#pragma unroll
        for (int j = 0; j < 4; ++j) {
            int co = m0 + tm + i;          // output channel 0..511
            int p  = n0 + tn + j;          // pixel within batch
            int head = co >> 6, d = co & 63;
            int y = p / HW_, xx = p % HW_;
            int wy = y / WS_, iy = y % WS_;
            int wx = xx / WS_, ix = xx % WS_;
            int w = wy * 8 + wx;
            int j49 = iy * WS_ + ix;
            size_t off = ((((size_t)b * HEADS_ + head) * NWIN_ + w) * WSQ_ + j49) * DH_ + d;
            Q[off] = __float2bfloat16(acc[i][j]);
        }
    }
}

// ---------------------------------------------------------------------------
// Kernel 3: windowed attention. One block per (b, head, window). 256 threads.
// q,k,v: bf16 [B][H][NWIN][49][64]; pos: fp32 [169][8]; O: bf16 [B][512][56][56]
// ---------------------------------------------------------------------------
__global__ __launch_bounds__(256) void attn_kernel(
    const bf16* __restrict__ Q, const bf16* __restrict__ Kt,
    const bf16* __restrict__ V, const float* __restrict__ pos,
    bf16* __restrict__ O) {
    __shared__ float qs[WSQ_][DH_ + 1];
    __shared__ float ks[WSQ_][DH_ + 1];
    __shared__ float vs[WSQ_][DH_ + 1];
    __shared__ float dots[WSQ_][WSQ_ + 1];
    int blk = blockIdx.x;
    int w = blk % NWIN_;
    int h = (blk / NWIN_) % HEADS_;
    int b = blk / (NWIN_ * HEADS_);
    size_t base = (((size_t)b * HEADS_ + h) * NWIN_ + w) * (WSQ_ * DH_);
    for (int e = threadIdx.x; e < WSQ_ * DH_; e += 256) {
        int i = e >> 6, d = e & 63;
        qs[i][d] = __bfloat162float(Q[base + e]);
        ks[i][d] = __bfloat162float(Kt[base + e]);
        vs[i][d] = __bfloat162float(V[base + e]);
    }
    __syncthreads();
    for (int e = threadIdx.x; e < WSQ_ * WSQ_; e += 256) {
        int i = e / WSQ_, j = e % WSQ_;
        float acc = 0.f;
#pragma unroll
        for (int d = 0; d < DH_; ++d) acc += qs[i][d] * ks[j][d];
        int xi = i / WS_, yi = i % WS_;
        int xj = j / WS_, yj = j % WS_;
        int rel = (xj - xi + 6) * 13 + (yj - yi + 6);
        dots[i][j] = acc * 0.125f + pos[rel * HEADS_ + h];
    }
    __syncthreads();
    if (threadIdx.x < WSQ_) {
        int i = threadIdx.x;
        float mx = -1e30f;
        for (int j = 0; j < WSQ_; ++j) mx = fmaxf(mx, dots[i][j]);
        float s = 0.f;
        for (int j = 0; j < WSQ_; ++j) { float e = __expf(dots[i][j] - mx); dots[i][j] = e; s += e; }
        float inv = 1.f / s;
        for (int j = 0; j < WSQ_; ++j) dots[i][j] *= inv;
    }
    __syncthreads();
    int wy = w >> 3, wx = w & 7;
    for (int e = threadIdx.x; e < WSQ_ * DH_; e += 256) {
        int i = e >> 6, d = e & 63;
        float acc = 0.f;
#pragma unroll
        for (int j = 0; j < WSQ_; ++j) acc += dots[i][j] * vs[j][d];
        int y = wy * WS_ + i / WS_, xx = wx * WS_ + i % WS_;
        size_t off = ((size_t)b * INNER_ + h * DH_ + d) * NPIX_ + y * HW_ + xx;
        O[off] = __float2bfloat16(acc);
    }
}

// ---------------------------------------------------------------------------
// Kernel 4: output pointwise GEMM 256x512 + bias -> fp32 d_out [B,256,56,56]
// ---------------------------------------------------------------------------
__global__ __launch_bounds__(256) void gemm_out_kernel(
    const float* __restrict__ A, const bf16* __restrict__ Bm,
    const float* __restrict__ bias, float* __restrict__ out, int K) {
    __shared__ float sA[16][65];
    __shared__ float sB[16][65];
    int tid = threadIdx.x;
    int m0 = blockIdx.x * 64;
    int n0 = blockIdx.y * 64;
    int b  = blockIdx.z;
    const bf16* Bp = Bm + (size_t)b * K * NPIX_;
    float acc[4][4] = {};
    int tm = (tid / 16) * 4;
    int tn = (tid % 16) * 4;
    for (int k0 = 0; k0 < K; k0 += 16) {
        {
            int mi = tid >> 2;
            int kb = (tid & 3) * 4;
            float4 av = *(const float4*)(A + (size_t)(m0 + mi) * K + k0 + kb);
            sA[kb + 0][mi] = av.x; sA[kb + 1][mi] = av.y;
            sA[kb + 2][mi] = av.z; sA[kb + 3][mi] = av.w;
        }
        {
            int kk = tid >> 4;
            int nb = (tid & 15) * 4;
            ushort4 bv = *(const ushort4*)(Bp + (size_t)(k0 + kk) * NPIX_ + n0 + nb);
            sB[kk][nb + 0] = u16tof(bv.x); sB[kk][nb + 1] = u16tof(bv.y);
            sB[kk][nb + 2] = u16tof(bv.z); sB[kk][nb + 3] = u16tof(bv.w);
        }
        __syncthreads();
#pragma unroll
        for (int kk = 0; kk < 16; ++kk) {
            float a0 = sA[kk][tm + 0], a1 = sA[kk][tm + 1];
            float a2 = sA[kk][tm + 2], a3 = sA[kk][tm + 3];
            float b0 = sB[kk][tn + 0], b1 = sB[kk][tn + 1];
            float b2 = sB[kk][tn + 2], b3 = sB[kk][tn + 3];
            acc[0][0] += a0 * b0; acc[0][1] += a0 * b1; acc[0][2] += a0 * b2; acc[0][3] += a0 * b3;
            acc[1][0] += a1 * b0; acc[1][1] += a1 * b1; acc[1][2] += a1 * b2; acc[1][3] += a1 * b3;
            acc[2][0] += a2 * b0; acc[2][1] += a2 * b1; acc[2][2] += a2 * b2; acc[2][3] += a2 * b3;
            acc[3][0] += a3 * b0; acc[3][1] += a3 * b1; acc[3][2] += a3 * b2; acc[3][3] += a3 * b3;
        }
        __syncthreads();
    }
#pragma unroll
    for (int i = 0; i < 4; ++i) {
#pragma unroll
        for (int j = 0; j < 4; ++j) {
            int co = m0 + tm + i;
            int p  = n0 + tn + j;
            out[((size_t)b * C_ + co) * NPIX_ + p] = acc[i][j] + bias[co];
        }
    }
}

// ---------------------------------------------------------------------------
extern "C" void kernel_launch(void* const* d_in, const int* in_sizes, int n_in,
                              void* d_out, int out_size, void* d_ws, size_t ws_size,
                              hipStream_t stream) {
    (void)in_sizes; (void)n_in; (void)out_size; (void)ws_size;
    const float* x     = (const float*)d_in[0];
    const float* pos   = (const float*)d_in[19];
    const float* out_w = (const float*)d_in[20];
    const float* out_b = (const float*)d_in[21];

    size_t tElems = (size_t)B_ * C_ * NPIX_;      // 12.8M
    size_t qElems = (size_t)B_ * INNER_ * NPIX_;  // 25.7M
    bf16* t = (bf16*)d_ws;
    bf16* q = t + tElems;
    bf16* k = q + qElems;
    bf16* v = k + qElems;
    bf16* o = v + qElems;
    bf16* qkv[3] = {q, k, v};

    dim3 blk(256);
    int dwBlocks = (int)(tElems / 256);
    dim3 gq(INNER_ / 64, NPIX_ / 64, B_);
    dim3 go(C_ / 64, NPIX_ / 64, B_);

    for (int p = 0; p < 3; ++p) {
        const float* dw = (const float*)d_in[1 + 6 * p + 0];
        const float* g  = (const float*)d_in[1 + 6 * p + 1];
        const float* bb = (const float*)d_in[1 + 6 * p + 2];
        const float* mm = (const float*)d_in[1 + 6 * p + 3];
        const float* vv = (const float*)d_in[1 + 6 * p + 4];
        const float* pw = (const float*)d_in[1 + 6 * p + 5];
        dwbn_kernel<<<dwBlocks, blk, 0, stream>>>(x, dw, g, bb, mm, vv, t);
        gemm_qkv_kernel<<<gq, blk, 0, stream>>>(pw, t, qkv[p], C_);
    }
    attn_kernel<<<B_ * HEADS_ * NWIN_, blk, 0, stream>>>(q, k, v, pos, o);
    gemm_out_kernel<<<go, blk, 0, stream>>>(out_w, o, out_b, (float*)d_out, INNER_);
}

// Round 2
// 883.178 us; speedup vs baseline: 2.0604x; 2.0604x over previous
//
#include <hip/hip_runtime.h>
#include <hip/hip_bf16.h>

typedef __hip_bfloat16 bf16;
typedef __bf16 bfv8 __attribute__((ext_vector_type(8)));
typedef float f32x4 __attribute__((ext_vector_type(4)));

constexpr int B_     = 16;
constexpr int C_     = 256;   // DIM
constexpr int INNER_ = 512;
constexpr int HEADS_ = 8;
constexpr int DH_    = 64;
constexpr int HW_    = 56;
constexpr int NPIX_  = HW_ * HW_;   // 3136
constexpr int WS_    = 7;
constexpr int WSQ_   = 49;
constexpr int NWIN_  = 64;          // 8x8 windows

// async global->LDS, 16 B per lane (global_load_lds_dwordx4)
static __device__ __forceinline__ void async16(const void* g, void* l) {
    __builtin_amdgcn_global_load_lds(
        (const __attribute__((address_space(1))) unsigned int*)g,
        (__attribute__((address_space(3))) unsigned int*)l, 16, 0, 0);
}

// ---------------------------------------------------------------------------
// fp32 -> bf16 weight conversion (tiny)
// ---------------------------------------------------------------------------
__global__ __launch_bounds__(256) void cvt_kernel(const float* __restrict__ s,
                                                  bf16* __restrict__ d, int n) {
    int i = blockIdx.x * 256 + threadIdx.x;
    if (i < n) d[i] = __float2bfloat16(s[i]);
}

// ---------------------------------------------------------------------------
// Kernel 1: depthwise 3x3 conv + BN -> bf16 t [B][3136 pix][256 ch] (ch contig)
// block: 64 pixels x 64 channels, LDS transpose for coalesced writes.
// ---------------------------------------------------------------------------
__global__ __launch_bounds__(256) void dwbn_kernel(
    const float* __restrict__ x, const float* __restrict__ dw,
    const float* __restrict__ g, const float* __restrict__ bb,
    const float* __restrict__ mm, const float* __restrict__ vv,
    bf16* __restrict__ t) {
    __shared__ bf16 sw[64][66];   // [pix][ch], pad 66 -> row stride 33 banks
    int p0 = blockIdx.x * 64, c0 = blockIdx.y * 64, b = blockIdx.z;
    int lane = threadIdx.x & 63, cq = threadIdx.x >> 6;
    int pix = p0 + lane;
    int y = pix / HW_, xx = pix % HW_;
#pragma unroll 4
    for (int i = 0; i < 16; ++i) {
        int c = c0 + cq * 16 + i;
        const float* xp = x + ((size_t)b * C_ + c) * NPIX_;
        const float* w9 = dw + c * 9;
        float acc = 0.f;
#pragma unroll
        for (int ky = 0; ky < 3; ++ky) {
            int yy = y + ky - 1;
            if (yy < 0 || yy >= HW_) continue;
#pragma unroll
            for (int kx = 0; kx < 3; ++kx) {
                int xc = xx + kx - 1;
                if (xc < 0 || xc >= HW_) continue;
                acc += w9[ky * 3 + kx] * xp[yy * HW_ + xc];
            }
        }
        float scale = g[c] * rsqrtf(vv[c] + 1e-5f);
        sw[lane][cq * 16 + i] = __float2bfloat16((acc - mm[c]) * scale + bb[c]);
    }
    __syncthreads();
    int cw = threadIdx.x & 63, pq = threadIdx.x >> 6;
#pragma unroll 4
    for (int j = 0; j < 16; ++j) {
        int p = pq + j * 4;
        t[((size_t)b * NPIX_ + p0 + p) * C_ + c0 + cw] = sw[p][cw];
    }
}

// ---------------------------------------------------------------------------
// Kernel 2: qkv pointwise GEMM via MFMA.
//   D[pix][ch] = sum_k T[pix][k] * W[ch][k]   (both k-contiguous bf16)
//   M=3136 pixels (25 tiles of 128, guarded), N=512 ch (4 tiles), K=256.
//   Block 256 thr = 4 waves, wave tile 64x64 (4x4 of 16x16x32 MFMA).
//   Epilogue: LDS C-tile -> windowed layout Q[b][h][w][j49][d], 16B stores.
// ---------------------------------------------------------------------------
__global__ __launch_bounds__(256) void gemm_qkv_mfma(
    const bf16* __restrict__ W, const bf16* __restrict__ T,
    bf16* __restrict__ Q) {
    __shared__ __align__(16) char smem[128 * 136 * 2];   // 34.8 KB
    bf16* sA = (bf16*)smem;            // 128 pix x 32 k   (8 KB)
    bf16* sB = sA + 128 * 32;          // 128 ch  x 32 k   (8 KB)
    bf16* sC = (bf16*)smem;            // 128 pix x 136 ch (aliased, post-loop)
    int tid = threadIdx.x;
    int c0 = blockIdx.x * 128;         // channel tile (fastest -> L2 reuse of T)
    int p0 = blockIdx.y * 128;         // pixel tile
    int b  = blockIdx.z;

    int row0 = tid >> 2;               // 0..63
    int kc   = (tid & 3) * 8;
    int pA0 = p0 + row0;       if (pA0 > NPIX_ - 1) pA0 = NPIX_ - 1;
    int pA1 = p0 + row0 + 64;  if (pA1 > NPIX_ - 1) pA1 = NPIX_ - 1;
    const bf16* gA0 = T + ((size_t)b * NPIX_ + pA0) * 256 + kc;
    const bf16* gA1 = T + ((size_t)b * NPIX_ + pA1) * 256 + kc;
    const bf16* gB0 = W + (size_t)(c0 + row0) * 256 + kc;
    const bf16* gB1 = W + (size_t)(c0 + row0 + 64) * 256 + kc;
    char* lA = (char*)sA + tid * 16;
    char* lB = (char*)sB + tid * 16;

    int lane = tid & 63, wv = tid >> 6;
    int wm = (wv >> 1) * 64;           // pixel offset of wave tile
    int wn = (wv & 1) * 64;            // channel offset
    int col16 = lane & 15, quad = lane >> 4;

    f32x4 acc[4][4] = {};
    for (int k0 = 0; k0 < 256; k0 += 32) {
        async16(gA0, lA);
        async16(gA1, lA + 4096);
        async16(gB0, lB);
        async16(gB1, lB + 4096);
        gA0 += 32; gA1 += 32; gB0 += 32; gB1 += 32;
        __syncthreads();
        bfv8 af[4], bfr[4];
#pragma unroll
        for (int mt = 0; mt < 4; ++mt)
            af[mt] = *(const bfv8*)(sA + (wm + mt * 16 + col16) * 32 + quad * 8);
#pragma unroll
        for (int nt = 0; nt < 4; ++nt)
            bfr[nt] = *(const bfv8*)(sB + (wn + nt * 16 + col16) * 32 + quad * 8);
#pragma unroll
        for (int mt = 0; mt < 4; ++mt)
#pragma unroll
            for (int nt = 0; nt < 4; ++nt)
                acc[mt][nt] = __builtin_amdgcn_mfma_f32_16x16x32_bf16(
                    af[mt], bfr[nt], acc[mt][nt], 0, 0, 0);
        __syncthreads();
    }
    // acc -> LDS C-tile (bf16). D mapping: row(pix)=quad*4+reg, col(ch)=lane&15
#pragma unroll
    for (int mt = 0; mt < 4; ++mt)
#pragma unroll
        for (int nt = 0; nt < 4; ++nt) {
            f32x4 a = acc[mt][nt];
#pragma unroll
            for (int r = 0; r < 4; ++r)
                sC[(wm + mt * 16 + quad * 4 + r) * 136 + wn + nt * 16 + col16] =
                    __float2bfloat16(a[r]);
        }
    __syncthreads();
    // writer: 8 channels per thread per iter, windowed scatter, 16-B stores
#pragma unroll
    for (int j = 0; j < 8; ++j) {
        int lin = j * 256 + tid;       // 0..2047 = 128 pix x 16 ch-groups
        int pixl = lin >> 4, chg = lin & 15;
        int p = p0 + pixl;
        if (p < NPIX_) {
            int ch = c0 + chg * 8;
            int h = ch >> 6, d = ch & 63;
            int yy = p / HW_, xx = p % HW_;
            int wdw = (yy / WS_) * 8 + (xx / WS_);
            int j49 = (yy % WS_) * WS_ + (xx % WS_);
            bfv8 vd = *(const bfv8*)(sC + pixl * 136 + chg * 8);
            *(bfv8*)(Q + ((((size_t)b * HEADS_ + h) * NWIN_ + wdw) * WSQ_ + j49) * DH_ + d) = vd;
        }
    }
}

// ---------------------------------------------------------------------------
// Kernel 3: windowed attention (unchanged VALU version; O-write now [b][pix][ch])
// ---------------------------------------------------------------------------
__global__ __launch_bounds__(256) void attn_kernel(
    const bf16* __restrict__ Q, const bf16* __restrict__ Kt,
    const bf16* __restrict__ V, const float* __restrict__ pos,
    bf16* __restrict__ O) {
    __shared__ float qs[WSQ_][DH_ + 1];
    __shared__ float ks[WSQ_][DH_ + 1];
    __shared__ float vs[WSQ_][DH_ + 1];
    __shared__ float dots[WSQ_][WSQ_ + 1];
    int blk = blockIdx.x;
    int w = blk % NWIN_;
    int h = (blk / NWIN_) % HEADS_;
    int b = blk / (NWIN_ * HEADS_);
    size_t base = (((size_t)b * HEADS_ + h) * NWIN_ + w) * (WSQ_ * DH_);
    for (int e = threadIdx.x; e < WSQ_ * DH_; e += 256) {
        int i = e >> 6, d = e & 63;
        qs[i][d] = __bfloat162float(Q[base + e]);
        ks[i][d] = __bfloat162float(Kt[base + e]);
        vs[i][d] = __bfloat162float(V[base + e]);
    }
    __syncthreads();
    for (int e = threadIdx.x; e < WSQ_ * WSQ_; e += 256) {
        int i = e / WSQ_, j = e % WSQ_;
        float acc = 0.f;
#pragma unroll
        for (int d = 0; d < DH_; ++d) acc += qs[i][d] * ks[j][d];
        int xi = i / WS_, yi = i % WS_;
        int xj = j / WS_, yj = j % WS_;
        int rel = (xj - xi + 6) * 13 + (yj - yi + 6);
        dots[i][j] = acc * 0.125f + pos[rel * HEADS_ + h];
    }
    __syncthreads();
    if (threadIdx.x < WSQ_) {
        int i = threadIdx.x;
        float mx = -1e30f;
        for (int j = 0; j < WSQ_; ++j) mx = fmaxf(mx, dots[i][j]);
        float s = 0.f;
        for (int j = 0; j < WSQ_; ++j) { float e = __expf(dots[i][j] - mx); dots[i][j] = e; s += e; }
        float inv = 1.f / s;
        for (int j = 0; j < WSQ_; ++j) dots[i][j] *= inv;
    }
    __syncthreads();
    int wy = w >> 3, wx = w & 7;
    for (int e = threadIdx.x; e < WSQ_ * DH_; e += 256) {
        int i = e >> 6, d = e & 63;
        float acc = 0.f;
#pragma unroll
        for (int j = 0; j < WSQ_; ++j) acc += dots[i][j] * vs[j][d];
        int y = wy * WS_ + i / WS_, xx = wx * WS_ + i % WS_;
        size_t off = ((size_t)b * NPIX_ + y * HW_ + xx) * INNER_ + h * DH_ + d;
        O[off] = __float2bfloat16(acc);
    }
}

// ---------------------------------------------------------------------------
// Kernel 4: output pointwise GEMM via MFMA + bias.
//   D[ch][pix] = sum_k Wo[ch][k] * O[pix][k];  M=256 ch (2 tiles), N=3136 pix
//   (25 tiles, guarded), K=512. fp32 stores, coalesced over pixels.
// ---------------------------------------------------------------------------
__global__ __launch_bounds__(256) void gemm_out_mfma(
    const bf16* __restrict__ W, const bf16* __restrict__ O,
    const float* __restrict__ bias, float* __restrict__ out) {
    __shared__ __align__(16) bf16 sA[128 * 32];   // 128 ch x 32 k
    __shared__ __align__(16) bf16 sB[128 * 32];   // 128 pix x 32 k
    int tid = threadIdx.x;
    int c0 = blockIdx.x * 128;
    int p0 = blockIdx.y * 128;
    int b  = blockIdx.z;

    int row0 = tid >> 2;
    int kc   = (tid & 3) * 8;
    int pB0 = p0 + row0;       if (pB0 > NPIX_ - 1) pB0 = NPIX_ - 1;
    int pB1 = p0 + row0 + 64;  if (pB1 > NPIX_ - 1) pB1 = NPIX_ - 1;
    const bf16* gA0 = W + (size_t)(c0 + row0) * 512 + kc;
    const bf16* gA1 = W + (size_t)(c0 + row0 + 64) * 512 + kc;
    const bf16* gB0 = O + ((size_t)b * NPIX_ + pB0) * 512 + kc;
    const bf16* gB1 = O + ((size_t)b * NPIX_ + pB1) * 512 + kc;
    char* lA = (char*)sA + tid * 16;
    char* lB = (char*)sB + tid * 16;

    int lane = tid & 63, wv = tid >> 6;
    int wm = (wv >> 1) * 64;          // channel offset
    int wn = (wv & 1) * 64;           // pixel offset
    int col16 = lane & 15, quad = lane >> 4;

    f32x4 acc[4][4] = {};
    for (int k0 = 0; k0 < 512; k0 += 32) {
        async16(gA0, lA);
        async16(gA1, lA + 4096);
        async16(gB0, lB);
        async16(gB1, lB + 4096);
        gA0 += 32; gA1 += 32; gB0 += 32; gB1 += 32;
        __syncthreads();
        bfv8 af[4], bfr[4];
#pragma unroll
        for (int mt = 0; mt < 4; ++mt)
            af[mt] = *(const bfv8*)(sA + (wm + mt * 16 + col16) * 32 + quad * 8);
#pragma unroll
        for (int nt = 0; nt < 4; ++nt)
            bfr[nt] = *(const bfv8*)(sB + (wn + nt * 16 + col16) * 32 + quad * 8);
#pragma unroll
        for (int mt = 0; mt < 4; ++mt)
#pragma unroll
            for (int nt = 0; nt < 4; ++nt)
                acc[mt][nt] = __builtin_amdgcn_mfma_f32_16x16x32_bf16(
                    af[mt], bfr[nt], acc[mt][nt], 0, 0, 0);
        __syncthreads();
    }
    // direct fp32 stores: row(ch)=quad*4+reg, col(pix)=lane&15 -> coalesced
#pragma unroll
    for (int mt = 0; mt < 4; ++mt) {
#pragma unroll
        for (int r = 0; r < 4; ++r) {
            int ch = c0 + wm + mt * 16 + quad * 4 + r;
            float bc = bias[ch];
#pragma unroll
            for (int nt = 0; nt < 4; ++nt) {
                int p = p0 + wn + nt * 16 + col16;
                if (p < NPIX_)
                    out[((size_t)b * C_ + ch) * NPIX_ + p] = acc[mt][nt][r] + bc;
            }
        }
    }
}

// ---------------------------------------------------------------------------
extern "C" void kernel_launch(void* const* d_in, const int* in_sizes, int n_in,
                              void* d_out, int out_size, void* d_ws, size_t ws_size,
                              hipStream_t stream) {
    (void)in_sizes; (void)n_in; (void)out_size; (void)ws_size;
    const float* x     = (const float*)d_in[0];
    const float* pos   = (const float*)d_in[19];
    const float* out_w = (const float*)d_in[20];
    const float* out_b = (const float*)d_in[21];

    size_t tElems = (size_t)B_ * NPIX_ * C_;        // 12.8M
    size_t qElems = (size_t)B_ * INNER_ * NPIX_;    // 25.7M
    bf16* t = (bf16*)d_ws;
    bf16* q = t + tElems;
    bf16* k = q + qElems;
    bf16* v = k + qElems;
    bf16* o = v + qElems;
    // bf16 weights aliased into dead regions:
    //   wq/wk/wv live in o's space (o written only later, by attn)
    //   wo lives in t's space (t dead after last gemm_qkv)
    bf16* wq = o;
    bf16* wk = wq + INNER_ * C_;
    bf16* wvv = wk + INNER_ * C_;
    bf16* wo = t;
    bf16* qkv[3] = {q, k, v};
    bf16* wts[3] = {wq, wk, wvv};

    dim3 blk(256);
    dim3 gDw(NPIX_ / 64, C_ / 64, B_);          // 49 x 4 x 16
    dim3 gQkv(INNER_ / 128, 25, B_);            // ch-tile fastest (L2 reuse of t)
    dim3 gOut(C_ / 128, 25, B_);

    for (int p = 0; p < 3; ++p)
        cvt_kernel<<<(INNER_ * C_) / 256, blk, 0, stream>>>(
            (const float*)d_in[1 + 6 * p + 5], wts[p], INNER_ * C_);

    for (int p = 0; p < 3; ++p) {
        const float* dwp = (const float*)d_in[1 + 6 * p + 0];
        const float* g   = (const float*)d_in[1 + 6 * p + 1];
        const float* bb  = (const float*)d_in[1 + 6 * p + 2];
        const float* mm  = (const float*)d_in[1 + 6 * p + 3];
        const float* vv  = (const float*)d_in[1 + 6 * p + 4];
        dwbn_kernel<<<gDw, blk, 0, stream>>>(x, dwp, g, bb, mm, vv, t);
        gemm_qkv_mfma<<<gQkv, blk, 0, stream>>>(wts[p], t, qkv[p]);
    }
    // t now dead -> convert out_w into its space
    cvt_kernel<<<(C_ * INNER_) / 256, blk, 0, stream>>>(out_w, wo, C_ * INNER_);
    attn_kernel<<<B_ * HEADS_ * NWIN_, blk, 0, stream>>>(q, k, v, pos, o);
    gemm_out_mfma<<<gOut, blk, 0, stream>>>(wo, o, out_b, (float*)d_out);
}

// Round 3
// 635.379 us; speedup vs baseline: 2.8640x; 1.3900x over previous
//
#include <hip/hip_runtime.h>
#include <hip/hip_bf16.h>

typedef __hip_bfloat16 bf16;
typedef __bf16 bfv8 __attribute__((ext_vector_type(8)));
typedef float f32x4 __attribute__((ext_vector_type(4)));

constexpr int B_     = 16;
constexpr int C_     = 256;   // DIM
constexpr int INNER_ = 512;
constexpr int HEADS_ = 8;
constexpr int DH_    = 64;
constexpr int HW_    = 56;
constexpr int NPIX_  = HW_ * HW_;   // 3136
constexpr int WS_    = 7;
constexpr int WSQ_   = 49;
constexpr int NWIN_  = 64;          // 8x8 windows

// async global->LDS, 16 B per lane (global_load_lds_dwordx4)
static __device__ __forceinline__ void async16(const void* g, void* l) {
    __builtin_amdgcn_global_load_lds(
        (const __attribute__((address_space(1))) unsigned int*)g,
        (__attribute__((address_space(3))) unsigned int*)l, 16, 0, 0);
}

// ---------------------------------------------------------------------------
// fp32 -> bf16 weight conversion (tiny)
// ---------------------------------------------------------------------------
__global__ __launch_bounds__(256) void cvt_kernel(const float* __restrict__ s,
                                                  bf16* __restrict__ d, int n) {
    int i = blockIdx.x * 256 + threadIdx.x;
    if (i < n) d[i] = __float2bfloat16(s[i]);
}

// ---------------------------------------------------------------------------
// Bias precompute: frag-ordered rel-pos bias, [8 h][4 band][64 lane][16 nt*4+r]
// pad cols (>=49) get -1e30 -> softmax masking is free in attn kernel.
// ---------------------------------------------------------------------------
__global__ __launch_bounds__(256) void bias_pre_kernel(
    const float* __restrict__ pos, float* __restrict__ biasf) {
    int h = blockIdx.x;
    int wv = threadIdx.x >> 6, lane = threadIdx.x & 63;
    int quad = lane >> 4, col16 = lane & 15;
    float* dst = biasf + (((size_t)h * 4 + wv) * 64 + lane) * 16;
#pragma unroll
    for (int nt = 0; nt < 4; ++nt)
#pragma unroll
        for (int r = 0; r < 4; ++r) {
            int row = wv * 16 + quad * 4 + r;
            int col = nt * 16 + col16;
            float v;
            if (col >= WSQ_) v = -1e30f;
            else if (row >= WSQ_) v = 0.f;
            else {
                int xi = row / WS_, yi = row % WS_;
                int xj = col / WS_, yj = col % WS_;
                int rel = (xj - xi + 6) * 13 + (yj - yi + 6);
                v = pos[rel * HEADS_ + h];
            }
            dst[nt * 4 + r] = v;
        }
}

// ---------------------------------------------------------------------------
// Kernel 1: depthwise 3x3 conv + BN -> bf16 t [B][3136 pix][256 ch] (ch contig)
// ---------------------------------------------------------------------------
__global__ __launch_bounds__(256) void dwbn_kernel(
    const float* __restrict__ x, const float* __restrict__ dw,
    const float* __restrict__ g, const float* __restrict__ bb,
    const float* __restrict__ mm, const float* __restrict__ vv,
    bf16* __restrict__ t) {
    __shared__ bf16 sw[64][66];
    int p0 = blockIdx.x * 64, c0 = blockIdx.y * 64, b = blockIdx.z;
    int lane = threadIdx.x & 63, cq = threadIdx.x >> 6;
    int pix = p0 + lane;
    int y = pix / HW_, xx = pix % HW_;
#pragma unroll 4
    for (int i = 0; i < 16; ++i) {
        int c = c0 + cq * 16 + i;
        const float* xp = x + ((size_t)b * C_ + c) * NPIX_;
        const float* w9 = dw + c * 9;
        float acc = 0.f;
#pragma unroll
        for (int ky = 0; ky < 3; ++ky) {
            int yy = y + ky - 1;
            if (yy < 0 || yy >= HW_) continue;
#pragma unroll
            for (int kx = 0; kx < 3; ++kx) {
                int xc = xx + kx - 1;
                if (xc < 0 || xc >= HW_) continue;
                acc += w9[ky * 3 + kx] * xp[yy * HW_ + xc];
            }
        }
        float scale = g[c] * rsqrtf(vv[c] + 1e-5f);
        sw[lane][cq * 16 + i] = __float2bfloat16((acc - mm[c]) * scale + bb[c]);
    }
    __syncthreads();
    int cw = threadIdx.x & 63, pq = threadIdx.x >> 6;
#pragma unroll 4
    for (int j = 0; j < 16; ++j) {
        int p = pq + j * 4;
        t[((size_t)b * NPIX_ + p0 + p) * C_ + c0 + cw] = sw[p][cw];
    }
}

// ---------------------------------------------------------------------------
// Kernel 2: qkv pointwise GEMM via MFMA (windowed-layout epilogue).
// ---------------------------------------------------------------------------
__global__ __launch_bounds__(256) void gemm_qkv_mfma(
    const bf16* __restrict__ W, const bf16* __restrict__ T,
    bf16* __restrict__ Q) {
    __shared__ __align__(16) char smem[128 * 136 * 2];
    bf16* sA = (bf16*)smem;
    bf16* sB = sA + 128 * 32;
    bf16* sC = (bf16*)smem;
    int tid = threadIdx.x;
    int c0 = blockIdx.x * 128;
    int p0 = blockIdx.y * 128;
    int b  = blockIdx.z;

    int row0 = tid >> 2;
    int kc   = (tid & 3) * 8;
    int pA0 = p0 + row0;       if (pA0 > NPIX_ - 1) pA0 = NPIX_ - 1;
    int pA1 = p0 + row0 + 64;  if (pA1 > NPIX_ - 1) pA1 = NPIX_ - 1;
    const bf16* gA0 = T + ((size_t)b * NPIX_ + pA0) * 256 + kc;
    const bf16* gA1 = T + ((size_t)b * NPIX_ + pA1) * 256 + kc;
    const bf16* gB0 = W + (size_t)(c0 + row0) * 256 + kc;
    const bf16* gB1 = W + (size_t)(c0 + row0 + 64) * 256 + kc;
    char* lA = (char*)sA + tid * 16;
    char* lB = (char*)sB + tid * 16;

    int lane = tid & 63, wv = tid >> 6;
    int wm = (wv >> 1) * 64;
    int wn = (wv & 1) * 64;
    int col16 = lane & 15, quad = lane >> 4;

    f32x4 acc[4][4] = {};
    for (int k0 = 0; k0 < 256; k0 += 32) {
        async16(gA0, lA);
        async16(gA1, lA + 4096);
        async16(gB0, lB);
        async16(gB1, lB + 4096);
        gA0 += 32; gA1 += 32; gB0 += 32; gB1 += 32;
        __syncthreads();
        bfv8 af[4], bfr[4];
#pragma unroll
        for (int mt = 0; mt < 4; ++mt)
            af[mt] = *(const bfv8*)(sA + (wm + mt * 16 + col16) * 32 + quad * 8);
#pragma unroll
        for (int nt = 0; nt < 4; ++nt)
            bfr[nt] = *(const bfv8*)(sB + (wn + nt * 16 + col16) * 32 + quad * 8);
#pragma unroll
        for (int mt = 0; mt < 4; ++mt)
#pragma unroll
            for (int nt = 0; nt < 4; ++nt)
                acc[mt][nt] = __builtin_amdgcn_mfma_f32_16x16x32_bf16(
                    af[mt], bfr[nt], acc[mt][nt], 0, 0, 0);
        __syncthreads();
    }
#pragma unroll
    for (int mt = 0; mt < 4; ++mt)
#pragma unroll
        for (int nt = 0; nt < 4; ++nt) {
            f32x4 a = acc[mt][nt];
#pragma unroll
            for (int r = 0; r < 4; ++r)
                sC[(wm + mt * 16 + quad * 4 + r) * 136 + wn + nt * 16 + col16] =
                    __float2bfloat16(a[r]);
        }
    __syncthreads();
#pragma unroll
    for (int j = 0; j < 8; ++j) {
        int lin = j * 256 + tid;
        int pixl = lin >> 4, chg = lin & 15;
        int p = p0 + pixl;
        if (p < NPIX_) {
            int ch = c0 + chg * 8;
            int h = ch >> 6, d = ch & 63;
            int yy = p / HW_, xx = p % HW_;
            int wdw = (yy / WS_) * 8 + (xx / WS_);
            int j49 = (yy % WS_) * WS_ + (xx % WS_);
            bfv8 vd = *(const bfv8*)(sC + pixl * 136 + chg * 8);
            *(bfv8*)(Q + ((((size_t)b * HEADS_ + h) * NWIN_ + wdw) * WSQ_ + j49) * DH_ + d) = vd;
        }
    }
}

// ---------------------------------------------------------------------------
// Kernel 3: windowed attention via MFMA. One block (4 waves) per (b,h,window).
// Wave wv owns S/O row band [16wv,16wv+16). S = Q K^T (16x16x32 MFMA),
// in-register softmax (shfl_xor width-16), P->LDS->A-frag, O = P V^T.
// O written as [b][pix][512] bf16 (k-contiguous for the output GEMM).
// ---------------------------------------------------------------------------
__global__ __launch_bounds__(256) void attn_mfma(
    const bf16* __restrict__ Q, const bf16* __restrict__ Kt,
    const bf16* __restrict__ V, const float* __restrict__ biasf,
    bf16* __restrict__ O) {
    __shared__ __align__(16) bf16 qs[64 * 72];
    __shared__ __align__(16) bf16 ks[64 * 72];
    __shared__ __align__(16) bf16 vt[64 * 72];   // V transposed: [d][j]
    __shared__ __align__(16) bf16 ps[64 * 72];
    int tid = threadIdx.x;
    int w = blockIdx.x & 63;
    int h = (blockIdx.x >> 6) & 7;
    int b = blockIdx.x >> 9;
    size_t base = (((size_t)b * HEADS_ + h) * NWIN_ + w) * (WSQ_ * DH_);

    // phase 0: zero vt (pad cols j>=49 MUST be 0: P_pad=0 x garbage -> NaN risk)
    {
        bfv8 z = {};
        bfv8* v16 = (bfv8*)vt;
        for (int c = tid; c < 576; c += 256) v16[c] = z;
    }
    __syncthreads();
    // phase 1: stage qs/ks (rows >=49 zeroed), vt transposed (valid j only)
    {
        bfv8 z = {};
        for (int c = tid; c < 512; c += 256) {   // 2 iters
            int row = c >> 3, col = (c & 7) * 8;
            bfv8 vq = z, vk = z;
            if (c < 392) {
                vq = *(const bfv8*)(Q + base + c * 8);
                vk = *(const bfv8*)(Kt + base + c * 8);
            }
            *(bfv8*)(qs + row * 72 + col) = vq;
            *(bfv8*)(ks + row * 72 + col) = vk;
        }
        for (int e = tid; e < WSQ_ * DH_; e += 256) {  // 13 iters
            int j = e >> 6, d = e & 63;
            vt[d * 72 + j] = V[base + e];
        }
    }
    __syncthreads();

    int lane = tid & 63, wv = tid >> 6;
    int band = wv * 16;
    int col16 = lane & 15, quad = lane >> 4;

    // S = Q K^T : rows band..band+15, all 64 cols (4 col-tiles)
    f32x4 sacc[4] = {};
    bfv8 aq0 = *(const bfv8*)(qs + (band + col16) * 72 + quad * 8);
    bfv8 aq1 = *(const bfv8*)(qs + (band + col16) * 72 + 32 + quad * 8);
#pragma unroll
    for (int nt = 0; nt < 4; ++nt) {
        bfv8 bk0 = *(const bfv8*)(ks + (nt * 16 + col16) * 72 + quad * 8);
        bfv8 bk1 = *(const bfv8*)(ks + (nt * 16 + col16) * 72 + 32 + quad * 8);
        sacc[nt] = __builtin_amdgcn_mfma_f32_16x16x32_bf16(aq0, bk0, sacc[nt], 0, 0, 0);
        sacc[nt] = __builtin_amdgcn_mfma_f32_16x16x32_bf16(aq1, bk1, sacc[nt], 0, 0, 0);
    }
    // bias (frag-ordered, pad cols = -1e30) + in-register softmax
    const float* bp = biasf + (((size_t)h * 4 + wv) * 64 + lane) * 16;
    f32x4 bias[4];
#pragma unroll
    for (int nt = 0; nt < 4; ++nt) bias[nt] = *(const f32x4*)(bp + nt * 4);
    float p[4][4];   // [nt][r] = unnormalized exp
    float inv[4];
#pragma unroll
    for (int r = 0; r < 4; ++r) {
        float s0 = sacc[0][r] * 0.125f + bias[0][r];
        float s1 = sacc[1][r] * 0.125f + bias[1][r];
        float s2 = sacc[2][r] * 0.125f + bias[2][r];
        float s3 = sacc[3][r] * 0.125f + bias[3][r];
        float mx = fmaxf(fmaxf(s0, s1), fmaxf(s2, s3));
        mx = fmaxf(mx, __shfl_xor(mx, 1, 16));
        mx = fmaxf(mx, __shfl_xor(mx, 2, 16));
        mx = fmaxf(mx, __shfl_xor(mx, 4, 16));
        mx = fmaxf(mx, __shfl_xor(mx, 8, 16));
        float e0 = __expf(s0 - mx), e1 = __expf(s1 - mx);
        float e2 = __expf(s2 - mx), e3 = __expf(s3 - mx);
        float sm = e0 + e1 + e2 + e3;
        sm += __shfl_xor(sm, 1, 16);
        sm += __shfl_xor(sm, 2, 16);
        sm += __shfl_xor(sm, 4, 16);
        sm += __shfl_xor(sm, 8, 16);
        p[0][r] = e0; p[1][r] = e1; p[2][r] = e2; p[3][r] = e3;
        inv[r] = 1.f / sm;   // applied at O store (same lane owns same rows)
    }
    // P -> LDS (C-layout -> A-operand layout round trip; own rows only)
#pragma unroll
    for (int nt = 0; nt < 4; ++nt)
#pragma unroll
        for (int r = 0; r < 4; ++r)
            ps[(band + quad * 4 + r) * 72 + nt * 16 + col16] = __float2bfloat16(p[nt][r]);
    // O = P V^T  (no barrier: wave reads only rows it wrote)
    f32x4 oacc[4] = {};
    bfv8 ap0 = *(const bfv8*)(ps + (band + col16) * 72 + quad * 8);
    bfv8 ap1 = *(const bfv8*)(ps + (band + col16) * 72 + 32 + quad * 8);
#pragma unroll
    for (int nt = 0; nt < 4; ++nt) {
        bfv8 bv0 = *(const bfv8*)(vt + (nt * 16 + col16) * 72 + quad * 8);
        bfv8 bv1 = *(const bfv8*)(vt + (nt * 16 + col16) * 72 + 32 + quad * 8);
        oacc[nt] = __builtin_amdgcn_mfma_f32_16x16x32_bf16(ap0, bv0, oacc[nt], 0, 0, 0);
        oacc[nt] = __builtin_amdgcn_mfma_f32_16x16x32_bf16(ap1, bv1, oacc[nt], 0, 0, 0);
    }
    int wy = w >> 3, wx = w & 7;
#pragma unroll
    for (int r = 0; r < 4; ++r) {
        int i = band + quad * 4 + r;
        if (i < WSQ_) {
            int py = wy * WS_ + i / WS_, px = wx * WS_ + i % WS_;
            size_t ob = ((size_t)b * NPIX_ + py * HW_ + px) * INNER_ + h * DH_;
            float sc = inv[r];
#pragma unroll
            for (int nt = 0; nt < 4; ++nt)
                O[ob + nt * 16 + col16] = __float2bfloat16(oacc[nt][r] * sc);
        }
    }
}

// ---------------------------------------------------------------------------
// Kernel 4: output pointwise GEMM via MFMA + bias (fp32 out).
// ---------------------------------------------------------------------------
__global__ __launch_bounds__(256) void gemm_out_mfma(
    const bf16* __restrict__ W, const bf16* __restrict__ O,
    const float* __restrict__ bias, float* __restrict__ out) {
    __shared__ __align__(16) bf16 sA[128 * 32];
    __shared__ __align__(16) bf16 sB[128 * 32];
    int tid = threadIdx.x;
    int c0 = blockIdx.x * 128;
    int p0 = blockIdx.y * 128;
    int b  = blockIdx.z;

    int row0 = tid >> 2;
    int kc   = (tid & 3) * 8;
    int pB0 = p0 + row0;       if (pB0 > NPIX_ - 1) pB0 = NPIX_ - 1;
    int pB1 = p0 + row0 + 64;  if (pB1 > NPIX_ - 1) pB1 = NPIX_ - 1;
    const bf16* gA0 = W + (size_t)(c0 + row0) * 512 + kc;
    const bf16* gA1 = W + (size_t)(c0 + row0 + 64) * 512 + kc;
    const bf16* gB0 = O + ((size_t)b * NPIX_ + pB0) * 512 + kc;
    const bf16* gB1 = O + ((size_t)b * NPIX_ + pB1) * 512 + kc;
    char* lA = (char*)sA + tid * 16;
    char* lB = (char*)sB + tid * 16;

    int lane = tid & 63, wv = tid >> 6;
    int wm = (wv >> 1) * 64;
    int wn = (wv & 1) * 64;
    int col16 = lane & 15, quad = lane >> 4;

    f32x4 acc[4][4] = {};
    for (int k0 = 0; k0 < 512; k0 += 32) {
        async16(gA0, lA);
        async16(gA1, lA + 4096);
        async16(gB0, lB);
        async16(gB1, lB + 4096);
        gA0 += 32; gA1 += 32; gB0 += 32; gB1 += 32;
        __syncthreads();
        bfv8 af[4], bfr[4];
#pragma unroll
        for (int mt = 0; mt < 4; ++mt)
            af[mt] = *(const bfv8*)(sA + (wm + mt * 16 + col16) * 32 + quad * 8);
#pragma unroll
        for (int nt = 0; nt < 4; ++nt)
            bfr[nt] = *(const bfv8*)(sB + (wn + nt * 16 + col16) * 32 + quad * 8);
#pragma unroll
        for (int mt = 0; mt < 4; ++mt)
#pragma unroll
            for (int nt = 0; nt < 4; ++nt)
                acc[mt][nt] = __builtin_amdgcn_mfma_f32_16x16x32_bf16(
                    af[mt], bfr[nt], acc[mt][nt], 0, 0, 0);
        __syncthreads();
    }
#pragma unroll
    for (int mt = 0; mt < 4; ++mt) {
#pragma unroll
        for (int r = 0; r < 4; ++r) {
            int ch = c0 + wm + mt * 16 + quad * 4 + r;
            float bc = bias[ch];
#pragma unroll
            for (int nt = 0; nt < 4; ++nt) {
                int p = p0 + wn + nt * 16 + col16;
                if (p < NPIX_)
                    out[((size_t)b * C_ + ch) * NPIX_ + p] = acc[mt][nt][r] + bc;
            }
        }
    }
}

// ---------------------------------------------------------------------------
extern "C" void kernel_launch(void* const* d_in, const int* in_sizes, int n_in,
                              void* d_out, int out_size, void* d_ws, size_t ws_size,
                              hipStream_t stream) {
    (void)in_sizes; (void)n_in; (void)out_size; (void)ws_size;
    const float* x     = (const float*)d_in[0];
    const float* pos   = (const float*)d_in[19];
    const float* out_w = (const float*)d_in[20];
    const float* out_b = (const float*)d_in[21];

    size_t tElems = (size_t)B_ * NPIX_ * C_;        // 12.8M
    size_t qElems = (size_t)B_ * INNER_ * NPIX_;    // 25.7M
    bf16* t = (bf16*)d_ws;
    bf16* q = t + tElems;
    bf16* k = q + qElems;
    bf16* v = k + qElems;
    bf16* o = v + qElems;
    // dead-region aliasing: wq/wk/wv in o's space (dead by attn time),
    // wo in t's space (t dead after last gemm_qkv). biasf after o.
    bf16* wq = o;
    bf16* wk = wq + INNER_ * C_;
    bf16* wvv = wk + INNER_ * C_;
    bf16* wo = t;
    float* biasf = (float*)(o + qElems);            // [8][4][64][16] fp32
    bf16* qkv[3] = {q, k, v};
    bf16* wts[3] = {wq, wk, wvv};

    dim3 blk(256);
    dim3 gDw(NPIX_ / 64, C_ / 64, B_);
    dim3 gQkv(INNER_ / 128, 25, B_);
    dim3 gOut(C_ / 128, 25, B_);

    bias_pre_kernel<<<HEADS_, blk, 0, stream>>>(pos, biasf);
    for (int p = 0; p < 3; ++p)
        cvt_kernel<<<(INNER_ * C_) / 256, blk, 0, stream>>>(
            (const float*)d_in[1 + 6 * p + 5], wts[p], INNER_ * C_);

    for (int p = 0; p < 3; ++p) {
        const float* dwp = (const float*)d_in[1 + 6 * p + 0];
        const float* g   = (const float*)d_in[1 + 6 * p + 1];
        const float* bb  = (const float*)d_in[1 + 6 * p + 2];
        const float* mm  = (const float*)d_in[1 + 6 * p + 3];
        const float* vv  = (const float*)d_in[1 + 6 * p + 4];
        dwbn_kernel<<<gDw, blk, 0, stream>>>(x, dwp, g, bb, mm, vv, t);
        gemm_qkv_mfma<<<gQkv, blk, 0, stream>>>(wts[p], t, qkv[p]);
    }
    cvt_kernel<<<(C_ * INNER_) / 256, blk, 0, stream>>>(out_w, wo, C_ * INNER_);
    attn_mfma<<<B_ * HEADS_ * NWIN_, blk, 0, stream>>>(q, k, v, biasf, o);
    gemm_out_mfma<<<gOut, blk, 0, stream>>>(wo, o, out_b, (float*)d_out);
}

// Round 4
// 437.494 us; speedup vs baseline: 4.1594x; 1.4523x over previous
//
#include <hip/hip_runtime.h>
#include <hip/hip_bf16.h>

typedef __hip_bfloat16 bf16;
typedef __bf16 bfv8 __attribute__((ext_vector_type(8)));
typedef float f32x4 __attribute__((ext_vector_type(4)));

constexpr int B_     = 16;
constexpr int C_     = 256;   // DIM
constexpr int INNER_ = 512;
constexpr int HEADS_ = 8;
constexpr int DH_    = 64;
constexpr int HW_    = 56;
constexpr int NPIX_  = HW_ * HW_;   // 3136
constexpr int WS_    = 7;
constexpr int WSQ_   = 49;
constexpr int NWIN_  = 64;          // 8x8 windows

// async global->LDS, 16 B per lane (global_load_lds_dwordx4)
static __device__ __forceinline__ void async16(const void* g, void* l) {
    __builtin_amdgcn_global_load_lds(
        (const __attribute__((address_space(1))) unsigned int*)g,
        (__attribute__((address_space(3))) unsigned int*)l, 16, 0, 0);
}

// ---------------------------------------------------------------------------
// fp32 -> bf16 weight conversion (tiny)
// ---------------------------------------------------------------------------
__global__ __launch_bounds__(256) void cvt_kernel(const float* __restrict__ s,
                                                  bf16* __restrict__ d, int n) {
    int i = blockIdx.x * 256 + threadIdx.x;
    if (i < n) d[i] = __float2bfloat16(s[i]);
}

// ---------------------------------------------------------------------------
// Fold BN into depthwise conv weights: wf[p][c][0..8]=w*s, [9]=b-m*s, [10..11]=0
// grid 3 blocks (one per projection), 256 threads (one per channel).
// ---------------------------------------------------------------------------
__global__ __launch_bounds__(256) void fold_kernel(
    const float* __restrict__ dw0, const float* __restrict__ g0,
    const float* __restrict__ b0, const float* __restrict__ m0,
    const float* __restrict__ v0,
    const float* __restrict__ dw1, const float* __restrict__ g1,
    const float* __restrict__ b1, const float* __restrict__ m1,
    const float* __restrict__ v1,
    const float* __restrict__ dw2, const float* __restrict__ g2,
    const float* __restrict__ b2, const float* __restrict__ m2,
    const float* __restrict__ v2,
    float* __restrict__ wf) {
    int p = blockIdx.x, c = threadIdx.x;
    const float* dw = p == 0 ? dw0 : (p == 1 ? dw1 : dw2);
    const float* g  = p == 0 ? g0  : (p == 1 ? g1  : g2);
    const float* bb = p == 0 ? b0  : (p == 1 ? b1  : b2);
    const float* mm = p == 0 ? m0  : (p == 1 ? m1  : m2);
    const float* vv = p == 0 ? v0  : (p == 1 ? v1  : v2);
    float s = g[c] * rsqrtf(vv[c] + 1e-5f);
    float* o = wf + (size_t)(p * 256 + c) * 12;
#pragma unroll
    for (int k = 0; k < 9; ++k) o[k] = dw[c * 9 + k] * s;
    o[9] = bb[c] - mm[c] * s;
    o[10] = 0.f; o[11] = 0.f;
}

// ---------------------------------------------------------------------------
// Bias precompute: frag-ordered rel-pos bias, [8 h][4 band][64 lane][16 nt*4+r]
// ---------------------------------------------------------------------------
__global__ __launch_bounds__(256) void bias_pre_kernel(
    const float* __restrict__ pos, float* __restrict__ biasf) {
    int h = blockIdx.x;
    int wv = threadIdx.x >> 6, lane = threadIdx.x & 63;
    int quad = lane >> 4, col16 = lane & 15;
    float* dst = biasf + (((size_t)h * 4 + wv) * 64 + lane) * 16;
#pragma unroll
    for (int nt = 0; nt < 4; ++nt)
#pragma unroll
        for (int r = 0; r < 4; ++r) {
            int row = wv * 16 + quad * 4 + r;
            int col = nt * 16 + col16;
            float v;
            if (col >= WSQ_) v = -1e30f;
            else if (row >= WSQ_) v = 0.f;
            else {
                int xi = row / WS_, yi = row % WS_;
                int xj = col / WS_, yj = col % WS_;
                int rel = (xj - xi + 6) * 13 + (yj - yi + 6);
                v = pos[rel * HEADS_ + h];
            }
            dst[nt * 4 + r] = v;
        }
}

// ---------------------------------------------------------------------------
// Kernel 1: fused depthwise 3x3 conv + folded BN for ALL THREE projections.
// x read once. Thread: (xo 0..7 -> 7-pixel x-strip) x (cg 0..31 -> 4 channels).
// Block covers one image row y x 128 channels. Outputs [b][pix][256ch] bf16.
// ---------------------------------------------------------------------------
__global__ __launch_bounds__(256) void dwbn3_kernel(
    const float* __restrict__ x, const float* __restrict__ wf,
    bf16* __restrict__ tq, bf16* __restrict__ tk, bf16* __restrict__ tv) {
    int y  = blockIdx.x;            // 0..55
    int c0 = blockIdx.y * 128;      // 0 or 128
    int b  = blockIdx.z;
    int xo = threadIdx.x & 7;       // 8 strips of 7 pixels
    int cg = threadIdx.x >> 3;      // 0..31
    int x0 = xo * 7;
    int cbase = c0 + cg * 4;

    unsigned short outu[3][7][4];
#pragma unroll
    for (int ci = 0; ci < 4; ++ci) {
        int cc = cbase + ci;
        const float* xp = x + (size_t)(b * C_ + cc) * NPIX_;
        float rr[3][9];
#pragma unroll
        for (int dy = 0; dy < 3; ++dy) {
            int row = y + dy - 1;
            if (row >= 0 && row < HW_) {
                const float* bp = xp + row * HW_;
                if (xo == 0) {
                    float4 a  = *(const float4*)(bp);
                    float4 b4 = *(const float4*)(bp + 4);
                    rr[dy][0] = 0.f;
                    rr[dy][1] = a.x;  rr[dy][2] = a.y;  rr[dy][3] = a.z;  rr[dy][4] = a.w;
                    rr[dy][5] = b4.x; rr[dy][6] = b4.y; rr[dy][7] = b4.z; rr[dy][8] = b4.w;
                } else if (xo == 7) {
                    float4 a  = *(const float4*)(bp + 48);
                    float4 b4 = *(const float4*)(bp + 52);
                    rr[dy][0] = a.x;  rr[dy][1] = a.y;  rr[dy][2] = a.z;  rr[dy][3] = a.w;
                    rr[dy][4] = b4.x; rr[dy][5] = b4.y; rr[dy][6] = b4.z; rr[dy][7] = b4.w;
                    rr[dy][8] = 0.f;
                } else {
                    float4 a  = *(const float4*)(bp + x0 - 1);
                    float4 b4 = *(const float4*)(bp + x0 + 3);
                    rr[dy][0] = a.x;  rr[dy][1] = a.y;  rr[dy][2] = a.z;  rr[dy][3] = a.w;
                    rr[dy][4] = b4.x; rr[dy][5] = b4.y; rr[dy][6] = b4.z; rr[dy][7] = b4.w;
                    rr[dy][8] = bp[x0 + 7];
                }
            } else {
#pragma unroll
                for (int k = 0; k < 9; ++k) rr[dy][k] = 0.f;
            }
        }
#pragma unroll
        for (int p = 0; p < 3; ++p) {
            const float* wp = wf + (size_t)(p * 256 + cc) * 12;
            float4 w0 = *(const float4*)(wp);
            float4 w1 = *(const float4*)(wp + 4);
            float4 w2 = *(const float4*)(wp + 8);   // w2.x = w8, w2.y = bias
#pragma unroll
            for (int px = 0; px < 7; ++px) {
                float acc = w2.y
                    + w0.x * rr[0][px]     + w0.y * rr[0][px + 1] + w0.z * rr[0][px + 2]
                    + w0.w * rr[1][px]     + w1.x * rr[1][px + 1] + w1.y * rr[1][px + 2]
                    + w1.z * rr[2][px]     + w1.w * rr[2][px + 1] + w2.x * rr[2][px + 2];
                bf16 hv = __float2bfloat16(acc);
                unsigned short u; __builtin_memcpy(&u, &hv, 2);
                outu[p][px][ci] = u;
            }
        }
    }
    bf16* outs[3] = {tq, tk, tv};
#pragma unroll
    for (int p = 0; p < 3; ++p)
#pragma unroll
        for (int px = 0; px < 7; ++px) {
            ushort4 vd = {outu[p][px][0], outu[p][px][1], outu[p][px][2], outu[p][px][3]};
            *(ushort4*)(outs[p] + ((size_t)b * NPIX_ + y * HW_ + x0 + px) * C_ + cbase) = vd;
        }
}

// ---------------------------------------------------------------------------
// Kernel 2: qkv pointwise GEMM via MFMA (windowed-layout epilogue).
// ---------------------------------------------------------------------------
__global__ __launch_bounds__(256) void gemm_qkv_mfma(
    const bf16* __restrict__ W, const bf16* __restrict__ T,
    bf16* __restrict__ Q) {
    __shared__ __align__(16) char smem[128 * 136 * 2];
    bf16* sA = (bf16*)smem;
    bf16* sB = sA + 128 * 32;
    bf16* sC = (bf16*)smem;
    int tid = threadIdx.x;
    int c0 = blockIdx.x * 128;
    int p0 = blockIdx.y * 128;
    int b  = blockIdx.z;

    int row0 = tid >> 2;
    int kc   = (tid & 3) * 8;
    int pA0 = p0 + row0;       if (pA0 > NPIX_ - 1) pA0 = NPIX_ - 1;
    int pA1 = p0 + row0 + 64;  if (pA1 > NPIX_ - 1) pA1 = NPIX_ - 1;
    const bf16* gA0 = T + ((size_t)b * NPIX_ + pA0) * 256 + kc;
    const bf16* gA1 = T + ((size_t)b * NPIX_ + pA1) * 256 + kc;
    const bf16* gB0 = W + (size_t)(c0 + row0) * 256 + kc;
    const bf16* gB1 = W + (size_t)(c0 + row0 + 64) * 256 + kc;
    char* lA = (char*)sA + tid * 16;
    char* lB = (char*)sB + tid * 16;

    int lane = tid & 63, wv = tid >> 6;
    int wm = (wv >> 1) * 64;
    int wn = (wv & 1) * 64;
    int col16 = lane & 15, quad = lane >> 4;

    f32x4 acc[4][4] = {};
    for (int k0 = 0; k0 < 256; k0 += 32) {
        async16(gA0, lA);
        async16(gA1, lA + 4096);
        async16(gB0, lB);
        async16(gB1, lB + 4096);
        gA0 += 32; gA1 += 32; gB0 += 32; gB1 += 32;
        __syncthreads();
        bfv8 af[4], bfr[4];
#pragma unroll
        for (int mt = 0; mt < 4; ++mt)
            af[mt] = *(const bfv8*)(sA + (wm + mt * 16 + col16) * 32 + quad * 8);
#pragma unroll
        for (int nt = 0; nt < 4; ++nt)
            bfr[nt] = *(const bfv8*)(sB + (wn + nt * 16 + col16) * 32 + quad * 8);
#pragma unroll
        for (int mt = 0; mt < 4; ++mt)
#pragma unroll
            for (int nt = 0; nt < 4; ++nt)
                acc[mt][nt] = __builtin_amdgcn_mfma_f32_16x16x32_bf16(
                    af[mt], bfr[nt], acc[mt][nt], 0, 0, 0);
        __syncthreads();
    }
#pragma unroll
    for (int mt = 0; mt < 4; ++mt)
#pragma unroll
        for (int nt = 0; nt < 4; ++nt) {
            f32x4 a = acc[mt][nt];
#pragma unroll
            for (int r = 0; r < 4; ++r)
                sC[(wm + mt * 16 + quad * 4 + r) * 136 + wn + nt * 16 + col16] =
                    __float2bfloat16(a[r]);
        }
    __syncthreads();
#pragma unroll
    for (int j = 0; j < 8; ++j) {
        int lin = j * 256 + tid;
        int pixl = lin >> 4, chg = lin & 15;
        int p = p0 + pixl;
        if (p < NPIX_) {
            int ch = c0 + chg * 8;
            int h = ch >> 6, d = ch & 63;
            int yy = p / HW_, xx = p % HW_;
            int wdw = (yy / WS_) * 8 + (xx / WS_);
            int j49 = (yy % WS_) * WS_ + (xx % WS_);
            bfv8 vd = *(const bfv8*)(sC + pixl * 136 + chg * 8);
            *(bfv8*)(Q + ((((size_t)b * HEADS_ + h) * NWIN_ + wdw) * WSQ_ + j49) * DH_ + d) = vd;
        }
    }
}

// ---------------------------------------------------------------------------
// Kernel 3: windowed attention via MFMA. One block (4 waves) per (b,h,window).
// ---------------------------------------------------------------------------
__global__ __launch_bounds__(256) void attn_mfma(
    const bf16* __restrict__ Q, const bf16* __restrict__ Kt,
    const bf16* __restrict__ V, const float* __restrict__ biasf,
    bf16* __restrict__ O) {
    __shared__ __align__(16) bf16 qs[64 * 72];
    __shared__ __align__(16) bf16 ks[64 * 72];
    __shared__ __align__(16) bf16 vt[64 * 72];   // V transposed: [d][j]
    __shared__ __align__(16) bf16 ps[64 * 72];
    int tid = threadIdx.x;
    int w = blockIdx.x & 63;
    int h = (blockIdx.x >> 6) & 7;
    int b = blockIdx.x >> 9;
    size_t base = (((size_t)b * HEADS_ + h) * NWIN_ + w) * (WSQ_ * DH_);

    {
        bfv8 z = {};
        bfv8* v16 = (bfv8*)vt;
        for (int c = tid; c < 576; c += 256) v16[c] = z;
    }
    __syncthreads();
    {
        bfv8 z = {};
        for (int c = tid; c < 512; c += 256) {
            int row = c >> 3, col = (c & 7) * 8;
            bfv8 vq = z, vk = z;
            if (c < 392) {
                vq = *(const bfv8*)(Q + base + c * 8);
                vk = *(const bfv8*)(Kt + base + c * 8);
            }
            *(bfv8*)(qs + row * 72 + col) = vq;
            *(bfv8*)(ks + row * 72 + col) = vk;
        }
        for (int e = tid; e < WSQ_ * DH_; e += 256) {
            int j = e >> 6, d = e & 63;
            vt[d * 72 + j] = V[base + e];
        }
    }
    __syncthreads();

    int lane = tid & 63, wv = tid >> 6;
    int band = wv * 16;
    int col16 = lane & 15, quad = lane >> 4;

    f32x4 sacc[4] = {};
    bfv8 aq0 = *(const bfv8*)(qs + (band + col16) * 72 + quad * 8);
    bfv8 aq1 = *(const bfv8*)(qs + (band + col16) * 72 + 32 + quad * 8);
#pragma unroll
    for (int nt = 0; nt < 4; ++nt) {
        bfv8 bk0 = *(const bfv8*)(ks + (nt * 16 + col16) * 72 + quad * 8);
        bfv8 bk1 = *(const bfv8*)(ks + (nt * 16 + col16) * 72 + 32 + quad * 8);
        sacc[nt] = __builtin_amdgcn_mfma_f32_16x16x32_bf16(aq0, bk0, sacc[nt], 0, 0, 0);
        sacc[nt] = __builtin_amdgcn_mfma_f32_16x16x32_bf16(aq1, bk1, sacc[nt], 0, 0, 0);
    }
    const float* bp = biasf + (((size_t)h * 4 + wv) * 64 + lane) * 16;
    f32x4 bias[4];
#pragma unroll
    for (int nt = 0; nt < 4; ++nt) bias[nt] = *(const f32x4*)(bp + nt * 4);
    float p[4][4];
    float inv[4];
#pragma unroll
    for (int r = 0; r < 4; ++r) {
        float s0 = sacc[0][r] * 0.125f + bias[0][r];
        float s1 = sacc[1][r] * 0.125f + bias[1][r];
        float s2 = sacc[2][r] * 0.125f + bias[2][r];
        float s3 = sacc[3][r] * 0.125f + bias[3][r];
        float mx = fmaxf(fmaxf(s0, s1), fmaxf(s2, s3));
        mx = fmaxf(mx, __shfl_xor(mx, 1, 16));
        mx = fmaxf(mx, __shfl_xor(mx, 2, 16));
        mx = fmaxf(mx, __shfl_xor(mx, 4, 16));
        mx = fmaxf(mx, __shfl_xor(mx, 8, 16));
        float e0 = __expf(s0 - mx), e1 = __expf(s1 - mx);
        float e2 = __expf(s2 - mx), e3 = __expf(s3 - mx);
        float sm = e0 + e1 + e2 + e3;
        sm += __shfl_xor(sm, 1, 16);
        sm += __shfl_xor(sm, 2, 16);
        sm += __shfl_xor(sm, 4, 16);
        sm += __shfl_xor(sm, 8, 16);
        p[0][r] = e0; p[1][r] = e1; p[2][r] = e2; p[3][r] = e3;
        inv[r] = 1.f / sm;
    }
#pragma unroll
    for (int nt = 0; nt < 4; ++nt)
#pragma unroll
        for (int r = 0; r < 4; ++r)
            ps[(band + quad * 4 + r) * 72 + nt * 16 + col16] = __float2bfloat16(p[nt][r]);
    f32x4 oacc[4] = {};
    bfv8 ap0 = *(const bfv8*)(ps + (band + col16) * 72 + quad * 8);
    bfv8 ap1 = *(const bfv8*)(ps + (band + col16) * 72 + 32 + quad * 8);
#pragma unroll
    for (int nt = 0; nt < 4; ++nt) {
        bfv8 bv0 = *(const bfv8*)(vt + (nt * 16 + col16) * 72 + quad * 8);
        bfv8 bv1 = *(const bfv8*)(vt + (nt * 16 + col16) * 72 + 32 + quad * 8);
        oacc[nt] = __builtin_amdgcn_mfma_f32_16x16x32_bf16(ap0, bv0, oacc[nt], 0, 0, 0);
        oacc[nt] = __builtin_amdgcn_mfma_f32_16x16x32_bf16(ap1, bv1, oacc[nt], 0, 0, 0);
    }
    int wy = w >> 3, wx = w & 7;
#pragma unroll
    for (int r = 0; r < 4; ++r) {
        int i = band + quad * 4 + r;
        if (i < WSQ_) {
            int py = wy * WS_ + i / WS_, px = wx * WS_ + i % WS_;
            size_t ob = ((size_t)b * NPIX_ + py * HW_ + px) * INNER_ + h * DH_;
            float sc = inv[r];
#pragma unroll
            for (int nt = 0; nt < 4; ++nt)
                O[ob + nt * 16 + col16] = __float2bfloat16(oacc[nt][r] * sc);
        }
    }
}

// ---------------------------------------------------------------------------
// Kernel 4: output pointwise GEMM via MFMA + bias (fp32 out).
// ---------------------------------------------------------------------------
__global__ __launch_bounds__(256) void gemm_out_mfma(
    const bf16* __restrict__ W, const bf16* __restrict__ O,
    const float* __restrict__ bias, float* __restrict__ out) {
    __shared__ __align__(16) bf16 sA[128 * 32];
    __shared__ __align__(16) bf16 sB[128 * 32];
    int tid = threadIdx.x;
    int c0 = blockIdx.x * 128;
    int p0 = blockIdx.y * 128;
    int b  = blockIdx.z;

    int row0 = tid >> 2;
    int kc   = (tid & 3) * 8;
    int pB0 = p0 + row0;       if (pB0 > NPIX_ - 1) pB0 = NPIX_ - 1;
    int pB1 = p0 + row0 + 64;  if (pB1 > NPIX_ - 1) pB1 = NPIX_ - 1;
    const bf16* gA0 = W + (size_t)(c0 + row0) * 512 + kc;
    const bf16* gA1 = W + (size_t)(c0 + row0 + 64) * 512 + kc;
    const bf16* gB0 = O + ((size_t)b * NPIX_ + pB0) * 512 + kc;
    const bf16* gB1 = O + ((size_t)b * NPIX_ + pB1) * 512 + kc;
    char* lA = (char*)sA + tid * 16;
    char* lB = (char*)sB + tid * 16;

    int lane = tid & 63, wv = tid >> 6;
    int wm = (wv >> 1) * 64;
    int wn = (wv & 1) * 64;
    int col16 = lane & 15, quad = lane >> 4;

    f32x4 acc[4][4] = {};
    for (int k0 = 0; k0 < 512; k0 += 32) {
        async16(gA0, lA);
        async16(gA1, lA + 4096);
        async16(gB0, lB);
        async16(gB1, lB + 4096);
        gA0 += 32; gA1 += 32; gB0 += 32; gB1 += 32;
        __syncthreads();
        bfv8 af[4], bfr[4];
#pragma unroll
        for (int mt = 0; mt < 4; ++mt)
            af[mt] = *(const bfv8*)(sA + (wm + mt * 16 + col16) * 32 + quad * 8);
#pragma unroll
        for (int nt = 0; nt < 4; ++nt)
            bfr[nt] = *(const bfv8*)(sB + (wn + nt * 16 + col16) * 32 + quad * 8);
#pragma unroll
        for (int mt = 0; mt < 4; ++mt)
#pragma unroll
            for (int nt = 0; nt < 4; ++nt)
                acc[mt][nt] = __builtin_amdgcn_mfma_f32_16x16x32_bf16(
                    af[mt], bfr[nt], acc[mt][nt], 0, 0, 0);
        __syncthreads();
    }
#pragma unroll
    for (int mt = 0; mt < 4; ++mt) {
#pragma unroll
        for (int r = 0; r < 4; ++r) {
            int ch = c0 + wm + mt * 16 + quad * 4 + r;
            float bc = bias[ch];
#pragma unroll
            for (int nt = 0; nt < 4; ++nt) {
                int p = p0 + wn + nt * 16 + col16;
                if (p < NPIX_)
                    out[((size_t)b * C_ + ch) * NPIX_ + p] = acc[mt][nt][r] + bc;
            }
        }
    }
}

// ---------------------------------------------------------------------------
extern "C" void kernel_launch(void* const* d_in, const int* in_sizes, int n_in,
                              void* d_out, int out_size, void* d_ws, size_t ws_size,
                              hipStream_t stream) {
    (void)in_sizes; (void)n_in; (void)out_size; (void)ws_size;
    const float* x     = (const float*)d_in[0];
    const float* pos   = (const float*)d_in[19];
    const float* out_w = (const float*)d_in[20];
    const float* out_b = (const float*)d_in[21];

    size_t tElems = (size_t)B_ * NPIX_ * C_;        // 12.845M
    size_t qElems = (size_t)B_ * INNER_ * NPIX_;    // 25.69M
    bf16* tq = (bf16*)d_ws;
    bf16* tk = tq + tElems;
    bf16* tv = tk + tElems;
    bf16* q  = tv + tElems;
    bf16* k  = q + qElems;
    bf16* v  = k + qElems;
    bf16* o  = tq;                                  // aliases tq+tk (dead by attn)
    float* wf = (float*)(v + qElems);               // [3][256][12] fp32
    bf16* wq = (bf16*)(wf + 3 * 256 * 12);
    bf16* wk = wq + INNER_ * C_;
    bf16* wvv = wk + INNER_ * C_;
    bf16* wo = wvv + INNER_ * C_;
    float* biasf = (float*)(wo + C_ * INNER_);      // [8][4][64][16] fp32
    bf16* qkv[3] = {q, k, v};
    bf16* t3[3]  = {tq, tk, tv};
    bf16* wts[3] = {wq, wk, wvv};

    dim3 blk(256);
    dim3 gDw(HW_, 2, B_);                           // 56 x 2 x 16
    dim3 gQkv(INNER_ / 128, 25, B_);
    dim3 gOut(C_ / 128, 25, B_);

    fold_kernel<<<3, blk, 0, stream>>>(
        (const float*)d_in[1],  (const float*)d_in[2],  (const float*)d_in[3],
        (const float*)d_in[4],  (const float*)d_in[5],
        (const float*)d_in[7],  (const float*)d_in[8],  (const float*)d_in[9],
        (const float*)d_in[10], (const float*)d_in[11],
        (const float*)d_in[13], (const float*)d_in[14], (const float*)d_in[15],
        (const float*)d_in[16], (const float*)d_in[17], wf);
    bias_pre_kernel<<<HEADS_, blk, 0, stream>>>(pos, biasf);
    for (int p = 0; p < 3; ++p)
        cvt_kernel<<<(INNER_ * C_) / 256, blk, 0, stream>>>(
            (const float*)d_in[1 + 6 * p + 5], wts[p], INNER_ * C_);
    cvt_kernel<<<(C_ * INNER_) / 256, blk, 0, stream>>>(out_w, wo, C_ * INNER_);

    dwbn3_kernel<<<gDw, blk, 0, stream>>>(x, wf, tq, tk, tv);
    for (int p = 0; p < 3; ++p)
        gemm_qkv_mfma<<<gQkv, blk, 0, stream>>>(wts[p], t3[p], qkv[p]);
    attn_mfma<<<B_ * HEADS_ * NWIN_, blk, 0, stream>>>(q, k, v, biasf, o);
    gemm_out_mfma<<<gOut, blk, 0, stream>>>(wo, o, out_b, (float*)d_out);
}

// Round 5
// 378.140 us; speedup vs baseline: 4.8123x; 1.1570x over previous
//
#include <hip/hip_runtime.h>
#include <hip/hip_bf16.h>

typedef __hip_bfloat16 bf16;
typedef __bf16 bfv8 __attribute__((ext_vector_type(8)));
typedef float f32x4 __attribute__((ext_vector_type(4)));

constexpr int B_     = 16;
constexpr int C_     = 256;   // DIM
constexpr int INNER_ = 512;
constexpr int HEADS_ = 8;
constexpr int DH_    = 64;
constexpr int HW_    = 56;
constexpr int NPIX_  = HW_ * HW_;   // 3136
constexpr int WS_    = 7;
constexpr int WSQ_   = 49;
constexpr int NWIN_  = 64;          // 8x8 windows

// async global->LDS, 16 B per lane (global_load_lds_dwordx4)
static __device__ __forceinline__ void async16(const void* g, void* l) {
    __builtin_amdgcn_global_load_lds(
        (const __attribute__((address_space(1))) unsigned int*)g,
        (__attribute__((address_space(3))) unsigned int*)l, 16, 0, 0);
}

// ---------------------------------------------------------------------------
// fp32 -> bf16 conversion of all 4 pointwise weight matrices (one launch)
// ---------------------------------------------------------------------------
__global__ __launch_bounds__(256) void cvt4_kernel(
    const float* __restrict__ s0, const float* __restrict__ s1,
    const float* __restrict__ s2, const float* __restrict__ s3,
    bf16* __restrict__ d) {
    int g = blockIdx.y;
    const float* s = g == 0 ? s0 : (g == 1 ? s1 : (g == 2 ? s2 : s3));
    int i = blockIdx.x * 256 + threadIdx.x;
    d[(size_t)g * (INNER_ * C_) + i] = __float2bfloat16(s[i]);
}

// ---------------------------------------------------------------------------
// Fold BN into depthwise conv weights: wf[p][c][0..8]=w*s, [9]=b-m*s
// ---------------------------------------------------------------------------
__global__ __launch_bounds__(256) void fold_kernel(
    const float* __restrict__ dw0, const float* __restrict__ g0,
    const float* __restrict__ b0, const float* __restrict__ m0,
    const float* __restrict__ v0,
    const float* __restrict__ dw1, const float* __restrict__ g1,
    const float* __restrict__ b1, const float* __restrict__ m1,
    const float* __restrict__ v1,
    const float* __restrict__ dw2, const float* __restrict__ g2,
    const float* __restrict__ b2, const float* __restrict__ m2,
    const float* __restrict__ v2,
    float* __restrict__ wf) {
    int p = blockIdx.x, c = threadIdx.x;
    const float* dw = p == 0 ? dw0 : (p == 1 ? dw1 : dw2);
    const float* g  = p == 0 ? g0  : (p == 1 ? g1  : g2);
    const float* bb = p == 0 ? b0  : (p == 1 ? b1  : b2);
    const float* mm = p == 0 ? m0  : (p == 1 ? m1  : m2);
    const float* vv = p == 0 ? v0  : (p == 1 ? v1  : v2);
    float s = g[c] * rsqrtf(vv[c] + 1e-5f);
    float* o = wf + (size_t)(p * 256 + c) * 12;
#pragma unroll
    for (int k = 0; k < 9; ++k) o[k] = dw[c * 9 + k] * s;
    o[9] = bb[c] - mm[c] * s;
    o[10] = 0.f; o[11] = 0.f;
}

// ---------------------------------------------------------------------------
// Bias precompute: frag-ordered rel-pos bias, [8 h][4 band][64 lane][16 nt*4+r]
// ---------------------------------------------------------------------------
__global__ __launch_bounds__(256) void bias_pre_kernel(
    const float* __restrict__ pos, float* __restrict__ biasf) {
    int h = blockIdx.x;
    int wv = threadIdx.x >> 6, lane = threadIdx.x & 63;
    int quad = lane >> 4, col16 = lane & 15;
    float* dst = biasf + (((size_t)h * 4 + wv) * 64 + lane) * 16;
#pragma unroll
    for (int nt = 0; nt < 4; ++nt)
#pragma unroll
        for (int r = 0; r < 4; ++r) {
            int row = wv * 16 + quad * 4 + r;
            int col = nt * 16 + col16;
            float v;
            if (col >= WSQ_) v = -1e30f;
            else if (row >= WSQ_) v = 0.f;
            else {
                int xi = row / WS_, yi = row % WS_;
                int xj = col / WS_, yj = col % WS_;
                int rel = (xj - xi + 6) * 13 + (yj - yi + 6);
                v = pos[rel * HEADS_ + h];
            }
            dst[nt * 4 + r] = v;
        }
}

// ---------------------------------------------------------------------------
// Kernel 1: fused dw-conv(3x3)+foldedBN, all 3 projections, LDS-staged.
// Block = (row y, 64 ch, b). LDS rows y-1..y+1 x 64ch x 61 cols (pads at 0,57).
// Compute: thread = (cg->2ch, xo->7px strip), sliding window, branch-free.
// ---------------------------------------------------------------------------
__global__ __launch_bounds__(256) void dwbn3_kernel(
    const float* __restrict__ x, const float* __restrict__ wf,
    bf16* __restrict__ tq, bf16* __restrict__ tk, bf16* __restrict__ tv) {
    __shared__ float xs[3 * 64 * 61];   // 46.8 KB
    int y  = blockIdx.x;
    int c0 = blockIdx.y * 64;
    int b  = blockIdx.z;
    int tid = threadIdx.x;
    // stage: 3 rows x 64 ch x 14 float4 = 2688 float4 loads, coalesced
    for (int i = tid; i < 2688; i += 256) {
        int row = i / 896;
        int rem = i - row * 896;
        int ch = rem / 14, s = rem - ch * 14;
        int yy = y + row - 1;
        float4 v4 = make_float4(0.f, 0.f, 0.f, 0.f);
        if (yy >= 0 && yy < HW_)                 // block-uniform per row
            v4 = *(const float4*)(x + (size_t)(b * C_ + c0 + ch) * NPIX_
                                    + yy * HW_ + s * 4);
        float* d = xs + (row * 64 + ch) * 61 + 1 + s * 4;
        d[0] = v4.x; d[1] = v4.y; d[2] = v4.z; d[3] = v4.w;
    }
    // zero the left/right pad columns
    for (int j = tid; j < 192; j += 256) {
        int row = j >> 6, ch = j & 63;
        xs[(row * 64 + ch) * 61] = 0.f;
        xs[(row * 64 + ch) * 61 + 57] = 0.f;
    }
    __syncthreads();

    int cg = tid & 31, xo = tid >> 5;
    int bcol = xo * 7;
    unsigned int pack[3][7];
#pragma unroll
    for (int ci = 0; ci < 2; ++ci) {
        int ch = cg * 2 + ci;
        float4 w[3][3];
#pragma unroll
        for (int p = 0; p < 3; ++p) {
            const float* wp = wf + (size_t)(p * 256 + c0 + ch) * 12;
            w[p][0] = *(const float4*)(wp);
            w[p][1] = *(const float4*)(wp + 4);
            w[p][2] = *(const float4*)(wp + 8);
        }
        const float* r0 = xs + ch * 61;
        const float* r1 = r0 + 64 * 61;
        const float* r2 = r1 + 64 * 61;
        float a00 = r0[bcol], a01 = r0[bcol + 1];
        float a10 = r1[bcol], a11 = r1[bcol + 1];
        float a20 = r2[bcol], a21 = r2[bcol + 1];
#pragma unroll
        for (int px = 0; px < 7; ++px) {
            float a02 = r0[bcol + px + 2];
            float a12 = r1[bcol + px + 2];
            float a22 = r2[bcol + px + 2];
#pragma unroll
            for (int p = 0; p < 3; ++p) {
                float acc = w[p][2].y
                    + w[p][0].x * a00 + w[p][0].y * a01 + w[p][0].z * a02
                    + w[p][0].w * a10 + w[p][1].x * a11 + w[p][1].y * a12
                    + w[p][1].z * a20 + w[p][1].w * a21 + w[p][2].x * a22;
                bf16 hv = __float2bfloat16(acc);
                unsigned short u; __builtin_memcpy(&u, &hv, 2);
                if (ci == 0) pack[p][px] = u;
                else         pack[p][px] |= ((unsigned int)u) << 16;
            }
            a00 = a01; a01 = a02; a10 = a11; a11 = a12; a20 = a21; a21 = a22;
        }
    }
    bf16* outs[3] = {tq, tk, tv};
    size_t pbase = ((size_t)b * NPIX_ + y * HW_ + bcol) * C_ + c0 + cg * 2;
#pragma unroll
    for (int p = 0; p < 3; ++p)
#pragma unroll
        for (int px = 0; px < 7; ++px)
            *(unsigned int*)(outs[p] + pbase + px * C_) = pack[p][px];
}

// ---------------------------------------------------------------------------
// Kernel 2: qkv pointwise GEMM via MFMA, all 3 projections in one launch.
// grid.z = p*16 + b. Epilogue writes windowed layout.
// ---------------------------------------------------------------------------
__global__ __launch_bounds__(256) void gemm_qkv_mfma(
    const bf16* __restrict__ Wbase, const bf16* __restrict__ Tbase,
    bf16* __restrict__ Qbase) {
    __shared__ __align__(16) char smem[128 * 136 * 2];
    bf16* sA = (bf16*)smem;
    bf16* sB = sA + 128 * 32;
    bf16* sC = (bf16*)smem;
    int tid = threadIdx.x;
    int c0 = blockIdx.x * 128;
    int p0 = blockIdx.y * 128;
    int zp = blockIdx.z >> 4;            // projection 0..2
    int b  = blockIdx.z & 15;
    const bf16* W = Wbase + (size_t)zp * (INNER_ * C_);
    const bf16* T = Tbase + (size_t)zp * ((size_t)B_ * NPIX_ * C_);
    bf16* Q = Qbase + (size_t)zp * ((size_t)B_ * INNER_ * NPIX_);

    int row0 = tid >> 2;
    int kc   = (tid & 3) * 8;
    int pA0 = p0 + row0;       if (pA0 > NPIX_ - 1) pA0 = NPIX_ - 1;
    int pA1 = p0 + row0 + 64;  if (pA1 > NPIX_ - 1) pA1 = NPIX_ - 1;
    const bf16* gA0 = T + ((size_t)b * NPIX_ + pA0) * 256 + kc;
    const bf16* gA1 = T + ((size_t)b * NPIX_ + pA1) * 256 + kc;
    const bf16* gB0 = W + (size_t)(c0 + row0) * 256 + kc;
    const bf16* gB1 = W + (size_t)(c0 + row0 + 64) * 256 + kc;
    char* lA = (char*)sA + tid * 16;
    char* lB = (char*)sB + tid * 16;

    int lane = tid & 63, wv = tid >> 6;
    int wm = (wv >> 1) * 64;
    int wn = (wv & 1) * 64;
    int col16 = lane & 15, quad = lane >> 4;

    f32x4 acc[4][4] = {};
    for (int k0 = 0; k0 < 256; k0 += 32) {
        async16(gA0, lA);
        async16(gA1, lA + 4096);
        async16(gB0, lB);
        async16(gB1, lB + 4096);
        gA0 += 32; gA1 += 32; gB0 += 32; gB1 += 32;
        __syncthreads();
        bfv8 af[4], bfr[4];
#pragma unroll
        for (int mt = 0; mt < 4; ++mt)
            af[mt] = *(const bfv8*)(sA + (wm + mt * 16 + col16) * 32 + quad * 8);
#pragma unroll
        for (int nt = 0; nt < 4; ++nt)
            bfr[nt] = *(const bfv8*)(sB + (wn + nt * 16 + col16) * 32 + quad * 8);
#pragma unroll
        for (int mt = 0; mt < 4; ++mt)
#pragma unroll
            for (int nt = 0; nt < 4; ++nt)
                acc[mt][nt] = __builtin_amdgcn_mfma_f32_16x16x32_bf16(
                    af[mt], bfr[nt], acc[mt][nt], 0, 0, 0);
        __syncthreads();
    }
#pragma unroll
    for (int mt = 0; mt < 4; ++mt)
#pragma unroll
        for (int nt = 0; nt < 4; ++nt) {
            f32x4 a = acc[mt][nt];
#pragma unroll
            for (int r = 0; r < 4; ++r)
                sC[(wm + mt * 16 + quad * 4 + r) * 136 + wn + nt * 16 + col16] =
                    __float2bfloat16(a[r]);
        }
    __syncthreads();
#pragma unroll
    for (int j = 0; j < 8; ++j) {
        int lin = j * 256 + tid;
        int pixl = lin >> 4, chg = lin & 15;
        int p = p0 + pixl;
        if (p < NPIX_) {
            int ch = c0 + chg * 8;
            int h = ch >> 6, d = ch & 63;
            int yy = p / HW_, xx = p % HW_;
            int wdw = (yy / WS_) * 8 + (xx / WS_);
            int j49 = (yy % WS_) * WS_ + (xx % WS_);
            bfv8 vd = *(const bfv8*)(sC + pixl * 136 + chg * 8);
            *(bfv8*)(Q + ((((size_t)b * HEADS_ + h) * NWIN_ + wdw) * WSQ_ + j49) * DH_ + d) = vd;
        }
    }
}

// ---------------------------------------------------------------------------
// Kernel 3: windowed attention via MFMA. One block (4 waves) per (b,h,window).
// ---------------------------------------------------------------------------
__global__ __launch_bounds__(256) void attn_mfma(
    const bf16* __restrict__ Q, const bf16* __restrict__ Kt,
    const bf16* __restrict__ V, const float* __restrict__ biasf,
    bf16* __restrict__ O) {
    __shared__ __align__(16) bf16 qs[64 * 72];
    __shared__ __align__(16) bf16 ks[64 * 72];
    __shared__ __align__(16) bf16 vt[64 * 72];   // V transposed: [d][j]
    __shared__ __align__(16) bf16 ps[64 * 72];
    int tid = threadIdx.x;
    int w = blockIdx.x & 63;
    int h = (blockIdx.x >> 6) & 7;
    int b = blockIdx.x >> 9;
    size_t base = (((size_t)b * HEADS_ + h) * NWIN_ + w) * (WSQ_ * DH_);

    {
        bfv8 z = {};
        bfv8* v16 = (bfv8*)vt;
        for (int c = tid; c < 576; c += 256) v16[c] = z;
    }
    __syncthreads();
    {
        bfv8 z = {};
        for (int c = tid; c < 512; c += 256) {
            int row = c >> 3, col = (c & 7) * 8;
            bfv8 vq = z, vk = z;
            if (c < 392) {
                vq = *(const bfv8*)(Q + base + c * 8);
                vk = *(const bfv8*)(Kt + base + c * 8);
            }
            *(bfv8*)(qs + row * 72 + col) = vq;
            *(bfv8*)(ks + row * 72 + col) = vk;
        }
        for (int e = tid; e < WSQ_ * DH_; e += 256) {
            int j = e >> 6, d = e & 63;
            vt[d * 72 + j] = V[base + e];
        }
    }
    __syncthreads();

    int lane = tid & 63, wv = tid >> 6;
    int band = wv * 16;
    int col16 = lane & 15, quad = lane >> 4;

    f32x4 sacc[4] = {};
    bfv8 aq0 = *(const bfv8*)(qs + (band + col16) * 72 + quad * 8);
    bfv8 aq1 = *(const bfv8*)(qs + (band + col16) * 72 + 32 + quad * 8);
#pragma unroll
    for (int nt = 0; nt < 4; ++nt) {
        bfv8 bk0 = *(const bfv8*)(ks + (nt * 16 + col16) * 72 + quad * 8);
        bfv8 bk1 = *(const bfv8*)(ks + (nt * 16 + col16) * 72 + 32 + quad * 8);
        sacc[nt] = __builtin_amdgcn_mfma_f32_16x16x32_bf16(aq0, bk0, sacc[nt], 0, 0, 0);
        sacc[nt] = __builtin_amdgcn_mfma_f32_16x16x32_bf16(aq1, bk1, sacc[nt], 0, 0, 0);
    }
    const float* bp = biasf + (((size_t)h * 4 + wv) * 64 + lane) * 16;
    f32x4 bias[4];
#pragma unroll
    for (int nt = 0; nt < 4; ++nt) bias[nt] = *(const f32x4*)(bp + nt * 4);
    float p[4][4];
    float inv[4];
#pragma unroll
    for (int r = 0; r < 4; ++r) {
        float s0 = sacc[0][r] * 0.125f + bias[0][r];
        float s1 = sacc[1][r] * 0.125f + bias[1][r];
        float s2 = sacc[2][r] * 0.125f + bias[2][r];
        float s3 = sacc[3][r] * 0.125f + bias[3][r];
        float mx = fmaxf(fmaxf(s0, s1), fmaxf(s2, s3));
        mx = fmaxf(mx, __shfl_xor(mx, 1, 16));
        mx = fmaxf(mx, __shfl_xor(mx, 2, 16));
        mx = fmaxf(mx, __shfl_xor(mx, 4, 16));
        mx = fmaxf(mx, __shfl_xor(mx, 8, 16));
        float e0 = __expf(s0 - mx), e1 = __expf(s1 - mx);
        float e2 = __expf(s2 - mx), e3 = __expf(s3 - mx);
        float sm = e0 + e1 + e2 + e3;
        sm += __shfl_xor(sm, 1, 16);
        sm += __shfl_xor(sm, 2, 16);
        sm += __shfl_xor(sm, 4, 16);
        sm += __shfl_xor(sm, 8, 16);
        p[0][r] = e0; p[1][r] = e1; p[2][r] = e2; p[3][r] = e3;
        inv[r] = 1.f / sm;
    }
#pragma unroll
    for (int nt = 0; nt < 4; ++nt)
#pragma unroll
        for (int r = 0; r < 4; ++r)
            ps[(band + quad * 4 + r) * 72 + nt * 16 + col16] = __float2bfloat16(p[nt][r]);
    f32x4 oacc[4] = {};
    bfv8 ap0 = *(const bfv8*)(ps + (band + col16) * 72 + quad * 8);
    bfv8 ap1 = *(const bfv8*)(ps + (band + col16) * 72 + 32 + quad * 8);
#pragma unroll
    for (int nt = 0; nt < 4; ++nt) {
        bfv8 bv0 = *(const bfv8*)(vt + (nt * 16 + col16) * 72 + quad * 8);
        bfv8 bv1 = *(const bfv8*)(vt + (nt * 16 + col16) * 72 + 32 + quad * 8);
        oacc[nt] = __builtin_amdgcn_mfma_f32_16x16x32_bf16(ap0, bv0, oacc[nt], 0, 0, 0);
        oacc[nt] = __builtin_amdgcn_mfma_f32_16x16x32_bf16(ap1, bv1, oacc[nt], 0, 0, 0);
    }
    int wy = w >> 3, wx = w & 7;
#pragma unroll
    for (int r = 0; r < 4; ++r) {
        int i = band + quad * 4 + r;
        if (i < WSQ_) {
            int py = wy * WS_ + i / WS_, px = wx * WS_ + i % WS_;
            size_t ob = ((size_t)b * NPIX_ + py * HW_ + px) * INNER_ + h * DH_;
            float sc = inv[r];
#pragma unroll
            for (int nt = 0; nt < 4; ++nt)
                O[ob + nt * 16 + col16] = __float2bfloat16(oacc[nt][r] * sc);
        }
    }
}

// ---------------------------------------------------------------------------
// Kernel 4: output pointwise GEMM via MFMA + bias (fp32 out).
// ---------------------------------------------------------------------------
__global__ __launch_bounds__(256) void gemm_out_mfma(
    const bf16* __restrict__ W, const bf16* __restrict__ O,
    const float* __restrict__ bias, float* __restrict__ out) {
    __shared__ __align__(16) bf16 sA[128 * 32];
    __shared__ __align__(16) bf16 sB[128 * 32];
    int tid = threadIdx.x;
    int c0 = blockIdx.x * 128;
    int p0 = blockIdx.y * 128;
    int b  = blockIdx.z;

    int row0 = tid >> 2;
    int kc   = (tid & 3) * 8;
    int pB0 = p0 + row0;       if (pB0 > NPIX_ - 1) pB0 = NPIX_ - 1;
    int pB1 = p0 + row0 + 64;  if (pB1 > NPIX_ - 1) pB1 = NPIX_ - 1;
    const bf16* gA0 = W + (size_t)(c0 + row0) * 512 + kc;
    const bf16* gA1 = W + (size_t)(c0 + row0 + 64) * 512 + kc;
    const bf16* gB0 = O + ((size_t)b * NPIX_ + pB0) * 512 + kc;
    const bf16* gB1 = O + ((size_t)b * NPIX_ + pB1) * 512 + kc;
    char* lA = (char*)sA + tid * 16;
    char* lB = (char*)sB + tid * 16;

    int lane = tid & 63, wv = tid >> 6;
    int wm = (wv >> 1) * 64;
    int wn = (wv & 1) * 64;
    int col16 = lane & 15, quad = lane >> 4;

    f32x4 acc[4][4] = {};
    for (int k0 = 0; k0 < 512; k0 += 32) {
        async16(gA0, lA);
        async16(gA1, lA + 4096);
        async16(gB0, lB);
        async16(gB1, lB + 4096);
        gA0 += 32; gA1 += 32; gB0 += 32; gB1 += 32;
        __syncthreads();
        bfv8 af[4], bfr[4];
#pragma unroll
        for (int mt = 0; mt < 4; ++mt)
            af[mt] = *(const bfv8*)(sA + (wm + mt * 16 + col16) * 32 + quad * 8);
#pragma unroll
        for (int nt = 0; nt < 4; ++nt)
            bfr[nt] = *(const bfv8*)(sB + (wn + nt * 16 + col16) * 32 + quad * 8);
#pragma unroll
        for (int mt = 0; mt < 4; ++mt)
#pragma unroll
            for (int nt = 0; nt < 4; ++nt)
                acc[mt][nt] = __builtin_amdgcn_mfma_f32_16x16x32_bf16(
                    af[mt], bfr[nt], acc[mt][nt], 0, 0, 0);
        __syncthreads();
    }
#pragma unroll
    for (int mt = 0; mt < 4; ++mt) {
#pragma unroll
        for (int r = 0; r < 4; ++r) {
            int ch = c0 + wm + mt * 16 + quad * 4 + r;
            float bc = bias[ch];
#pragma unroll
            for (int nt = 0; nt < 4; ++nt) {
                int p = p0 + wn + nt * 16 + col16;
                if (p < NPIX_)
                    out[((size_t)b * C_ + ch) * NPIX_ + p] = acc[mt][nt][r] + bc;
            }
        }
    }
}

// ---------------------------------------------------------------------------
extern "C" void kernel_launch(void* const* d_in, const int* in_sizes, int n_in,
                              void* d_out, int out_size, void* d_ws, size_t ws_size,
                              hipStream_t stream) {
    (void)in_sizes; (void)n_in; (void)out_size; (void)ws_size;
    const float* x     = (const float*)d_in[0];
    const float* pos   = (const float*)d_in[19];
    const float* out_w = (const float*)d_in[20];
    const float* out_b = (const float*)d_in[21];

    size_t tElems = (size_t)B_ * NPIX_ * C_;        // 12.845M
    size_t qElems = (size_t)B_ * INNER_ * NPIX_;    // 25.69M
    bf16* tq = (bf16*)d_ws;                         // t's: [3][B][pix][256]
    bf16* q  = tq + 3 * tElems;                     // qkv: [3][B][h][w][49][64]
    bf16* o  = tq;                                  // aliases tq+tk (dead by attn)
    float* wf = (float*)(q + 3 * qElems);           // [3][256][12] fp32
    bf16* wq = (bf16*)(wf + 3 * 256 * 12);          // [4][512*256] bf16 weights
    bf16* wo = wq + 3 * (INNER_ * C_);
    float* biasf = (float*)(wo + C_ * INNER_);      // [8][4][64][16] fp32

    dim3 blk(256);
    dim3 gDw(HW_, 4, B_);                           // 56 x 4 x 16
    dim3 gQkv(INNER_ / 128, 25, 3 * B_);            // z = p*16 + b
    dim3 gOut(C_ / 128, 25, B_);
    dim3 gCvt((INNER_ * C_) / 256, 4);

    fold_kernel<<<3, blk, 0, stream>>>(
        (const float*)d_in[1],  (const float*)d_in[2],  (const float*)d_in[3],
        (const float*)d_in[4],  (const float*)d_in[5],
        (const float*)d_in[7],  (const float*)d_in[8],  (const float*)d_in[9],
        (const float*)d_in[10], (const float*)d_in[11],
        (const float*)d_in[13], (const float*)d_in[14], (const float*)d_in[15],
        (const float*)d_in[16], (const float*)d_in[17], wf);
    bias_pre_kernel<<<HEADS_, blk, 0, stream>>>(pos, biasf);
    cvt4_kernel<<<gCvt, blk, 0, stream>>>(
        (const float*)d_in[6], (const float*)d_in[12], (const float*)d_in[18],
        out_w, wq);

    dwbn3_kernel<<<gDw, blk, 0, stream>>>(x, wf, tq, tq + tElems, tq + 2 * tElems);
    gemm_qkv_mfma<<<gQkv, blk, 0, stream>>>(wq, tq, q);
    attn_mfma<<<B_ * HEADS_ * NWIN_, blk, 0, stream>>>(
        q, q + qElems, q + 2 * qElems, biasf, o);
    gemm_out_mfma<<<gOut, blk, 0, stream>>>(wo, o, out_b, (float*)d_out);
}

// Round 6
// 358.238 us; speedup vs baseline: 5.0796x; 1.0556x over previous
//
#include <hip/hip_runtime.h>
#include <hip/hip_bf16.h>

typedef __hip_bfloat16 bf16;
typedef __bf16 bfv8 __attribute__((ext_vector_type(8)));
typedef float f32x4 __attribute__((ext_vector_type(4)));

constexpr int B_     = 16;
constexpr int C_     = 256;   // DIM
constexpr int INNER_ = 512;
constexpr int HEADS_ = 8;
constexpr int DH_    = 64;
constexpr int HW_    = 56;
constexpr int NPIX_  = HW_ * HW_;   // 3136
constexpr int WS_    = 7;
constexpr int WSQ_   = 49;
constexpr int NWIN_  = 64;          // 8x8 windows

// async global->LDS, 16 B per lane (global_load_lds_dwordx4)
static __device__ __forceinline__ void async16(const void* g, void* l) {
    __builtin_amdgcn_global_load_lds(
        (const __attribute__((address_space(1))) unsigned int*)g,
        (__attribute__((address_space(3))) unsigned int*)l, 16, 0, 0);
}

// ---------------------------------------------------------------------------
// Merged setup: [0,2048) cvt of 4 weight mats; [2048,2051) BN-fold; [2051,2059) bias
// ---------------------------------------------------------------------------
__global__ __launch_bounds__(256) void setup_kernel(
    const float* __restrict__ pw0, const float* __restrict__ pw1,
    const float* __restrict__ pw2, const float* __restrict__ pw3,
    bf16* __restrict__ wq,
    const float* __restrict__ dw0, const float* __restrict__ g0,
    const float* __restrict__ b0, const float* __restrict__ m0,
    const float* __restrict__ v0,
    const float* __restrict__ dw1, const float* __restrict__ g1,
    const float* __restrict__ b1, const float* __restrict__ m1,
    const float* __restrict__ v1,
    const float* __restrict__ dw2, const float* __restrict__ g2,
    const float* __restrict__ b2, const float* __restrict__ m2,
    const float* __restrict__ v2,
    float* __restrict__ wf,
    const float* __restrict__ pos, float* __restrict__ biasf) {
    int bx = blockIdx.x;
    if (bx < 2048) {
        int g = bx >> 9;
        const float* s = g == 0 ? pw0 : (g == 1 ? pw1 : (g == 2 ? pw2 : pw3));
        int i = (bx & 511) * 256 + threadIdx.x;
        wq[(size_t)g * (INNER_ * C_) + i] = __float2bfloat16(s[i]);
    } else if (bx < 2051) {
        int p = bx - 2048, c = threadIdx.x;
        const float* dw = p == 0 ? dw0 : (p == 1 ? dw1 : dw2);
        const float* g  = p == 0 ? g0  : (p == 1 ? g1  : g2);
        const float* bb = p == 0 ? b0  : (p == 1 ? b1  : b2);
        const float* mm = p == 0 ? m0  : (p == 1 ? m1  : m2);
        const float* vv = p == 0 ? v0  : (p == 1 ? v1  : v2);
        float s = g[c] * rsqrtf(vv[c] + 1e-5f);
        float* o = wf + (size_t)(p * 256 + c) * 12;
#pragma unroll
        for (int k = 0; k < 9; ++k) o[k] = dw[c * 9 + k] * s;
        o[9] = bb[c] - mm[c] * s;
        o[10] = 0.f; o[11] = 0.f;
    } else {
        int h = bx - 2051;
        int wv = threadIdx.x >> 6, lane = threadIdx.x & 63;
        int quad = lane >> 4, col16 = lane & 15;
        float* dst = biasf + (((size_t)h * 4 + wv) * 64 + lane) * 16;
#pragma unroll
        for (int nt = 0; nt < 4; ++nt)
#pragma unroll
            for (int r = 0; r < 4; ++r) {
                int row = wv * 16 + quad * 4 + r;
                int col = nt * 16 + col16;
                float v;
                if (col >= WSQ_) v = -1e30f;
                else if (row >= WSQ_) v = 0.f;
                else {
                    int xi = row / WS_, yi = row % WS_;
                    int xj = col / WS_, yj = col % WS_;
                    int rel = (xj - xi + 6) * 13 + (yj - yi + 6);
                    v = pos[rel * HEADS_ + h];
                }
                dst[nt * 4 + r] = v;
            }
    }
}

// ---------------------------------------------------------------------------
// Kernel 1: fused dw-conv(3x3)+foldedBN, all 3 projections, LDS-staged.
// ---------------------------------------------------------------------------
__global__ __launch_bounds__(256) void dwbn3_kernel(
    const float* __restrict__ x, const float* __restrict__ wf,
    bf16* __restrict__ tq, bf16* __restrict__ tk, bf16* __restrict__ tv) {
    __shared__ float xs[3 * 64 * 61];   // 46.8 KB
    int y  = blockIdx.x;
    int c0 = blockIdx.y * 64;
    int b  = blockIdx.z;
    int tid = threadIdx.x;
    for (int i = tid; i < 2688; i += 256) {
        int row = i / 896;
        int rem = i - row * 896;
        int ch = rem / 14, s = rem - ch * 14;
        int yy = y + row - 1;
        float4 v4 = make_float4(0.f, 0.f, 0.f, 0.f);
        if (yy >= 0 && yy < HW_)
            v4 = *(const float4*)(x + (size_t)(b * C_ + c0 + ch) * NPIX_
                                    + yy * HW_ + s * 4);
        float* d = xs + (row * 64 + ch) * 61 + 1 + s * 4;
        d[0] = v4.x; d[1] = v4.y; d[2] = v4.z; d[3] = v4.w;
    }
    for (int j = tid; j < 192; j += 256) {
        int row = j >> 6, ch = j & 63;
        xs[(row * 64 + ch) * 61] = 0.f;
        xs[(row * 64 + ch) * 61 + 57] = 0.f;
    }
    __syncthreads();

    int cg = tid & 31, xo = tid >> 5;
    int bcol = xo * 7;
    unsigned int pack[3][7];
#pragma unroll
    for (int ci = 0; ci < 2; ++ci) {
        int ch = cg * 2 + ci;
        float4 w[3][3];
#pragma unroll
        for (int p = 0; p < 3; ++p) {
            const float* wp = wf + (size_t)(p * 256 + c0 + ch) * 12;
            w[p][0] = *(const float4*)(wp);
            w[p][1] = *(const float4*)(wp + 4);
            w[p][2] = *(const float4*)(wp + 8);
        }
        const float* r0 = xs + ch * 61;
        const float* r1 = r0 + 64 * 61;
        const float* r2 = r1 + 64 * 61;
        float a00 = r0[bcol], a01 = r0[bcol + 1];
        float a10 = r1[bcol], a11 = r1[bcol + 1];
        float a20 = r2[bcol], a21 = r2[bcol + 1];
#pragma unroll
        for (int px = 0; px < 7; ++px) {
            float a02 = r0[bcol + px + 2];
            float a12 = r1[bcol + px + 2];
            float a22 = r2[bcol + px + 2];
#pragma unroll
            for (int p = 0; p < 3; ++p) {
                float acc = w[p][2].y
                    + w[p][0].x * a00 + w[p][0].y * a01 + w[p][0].z * a02
                    + w[p][0].w * a10 + w[p][1].x * a11 + w[p][1].y * a12
                    + w[p][1].z * a20 + w[p][1].w * a21 + w[p][2].x * a22;
                bf16 hv = __float2bfloat16(acc);
                unsigned short u; __builtin_memcpy(&u, &hv, 2);
                if (ci == 0) pack[p][px] = u;
                else         pack[p][px] |= ((unsigned int)u) << 16;
            }
            a00 = a01; a01 = a02; a10 = a11; a11 = a12; a20 = a21; a21 = a22;
        }
    }
    bf16* outs[3] = {tq, tk, tv};
    size_t pbase = ((size_t)b * NPIX_ + y * HW_ + bcol) * C_ + c0 + cg * 2;
#pragma unroll
    for (int p = 0; p < 3; ++p)
#pragma unroll
        for (int px = 0; px < 7; ++px)
            *(unsigned int*)(outs[p] + pbase + px * C_) = pack[p][px];
}

// ---------------------------------------------------------------------------
// Kernel 2: qkv pointwise GEMM via MFMA, all 3 projections in one launch.
// Q projection (zp==0) is pre-scaled by 1/8 (exact in bf16) for attention.
// ---------------------------------------------------------------------------
__global__ __launch_bounds__(256) void gemm_qkv_mfma(
    const bf16* __restrict__ Wbase, const bf16* __restrict__ Tbase,
    bf16* __restrict__ Qbase) {
    __shared__ __align__(16) char smem[128 * 136 * 2];
    bf16* sA = (bf16*)smem;
    bf16* sB = sA + 128 * 32;
    bf16* sC = (bf16*)smem;
    int tid = threadIdx.x;
    int c0 = blockIdx.x * 128;
    int p0 = blockIdx.y * 128;
    int zp = blockIdx.z >> 4;            // projection 0..2
    int b  = blockIdx.z & 15;
    const bf16* W = Wbase + (size_t)zp * (INNER_ * C_);
    const bf16* T = Tbase + (size_t)zp * ((size_t)B_ * NPIX_ * C_);
    bf16* Q = Qbase + (size_t)zp * ((size_t)B_ * INNER_ * NPIX_);
    float qscale = (zp == 0) ? 0.125f : 1.0f;

    int row0 = tid >> 2;
    int kc   = (tid & 3) * 8;
    int pA0 = p0 + row0;       if (pA0 > NPIX_ - 1) pA0 = NPIX_ - 1;
    int pA1 = p0 + row0 + 64;  if (pA1 > NPIX_ - 1) pA1 = NPIX_ - 1;
    const bf16* gA0 = T + ((size_t)b * NPIX_ + pA0) * 256 + kc;
    const bf16* gA1 = T + ((size_t)b * NPIX_ + pA1) * 256 + kc;
    const bf16* gB0 = W + (size_t)(c0 + row0) * 256 + kc;
    const bf16* gB1 = W + (size_t)(c0 + row0 + 64) * 256 + kc;
    char* lA = (char*)sA + tid * 16;
    char* lB = (char*)sB + tid * 16;

    int lane = tid & 63, wv = tid >> 6;
    int wm = (wv >> 1) * 64;
    int wn = (wv & 1) * 64;
    int col16 = lane & 15, quad = lane >> 4;

    f32x4 acc[4][4] = {};
    for (int k0 = 0; k0 < 256; k0 += 32) {
        async16(gA0, lA);
        async16(gA1, lA + 4096);
        async16(gB0, lB);
        async16(gB1, lB + 4096);
        gA0 += 32; gA1 += 32; gB0 += 32; gB1 += 32;
        __syncthreads();
        bfv8 af[4], bfr[4];
#pragma unroll
        for (int mt = 0; mt < 4; ++mt)
            af[mt] = *(const bfv8*)(sA + (wm + mt * 16 + col16) * 32 + quad * 8);
#pragma unroll
        for (int nt = 0; nt < 4; ++nt)
            bfr[nt] = *(const bfv8*)(sB + (wn + nt * 16 + col16) * 32 + quad * 8);
#pragma unroll
        for (int mt = 0; mt < 4; ++mt)
#pragma unroll
            for (int nt = 0; nt < 4; ++nt)
                acc[mt][nt] = __builtin_amdgcn_mfma_f32_16x16x32_bf16(
                    af[mt], bfr[nt], acc[mt][nt], 0, 0, 0);
        __syncthreads();
    }
#pragma unroll
    for (int mt = 0; mt < 4; ++mt)
#pragma unroll
        for (int nt = 0; nt < 4; ++nt) {
            f32x4 a = acc[mt][nt];
#pragma unroll
            for (int r = 0; r < 4; ++r)
                sC[(wm + mt * 16 + quad * 4 + r) * 136 + wn + nt * 16 + col16] =
                    __float2bfloat16(a[r] * qscale);
        }
    __syncthreads();
#pragma unroll
    for (int j = 0; j < 8; ++j) {
        int lin = j * 256 + tid;
        int pixl = lin >> 4, chg = lin & 15;
        int p = p0 + pixl;
        if (p < NPIX_) {
            int ch = c0 + chg * 8;
            int h = ch >> 6, d = ch & 63;
            int yy = p / HW_, xx = p % HW_;
            int wdw = (yy / WS_) * 8 + (xx / WS_);
            int j49 = (yy % WS_) * WS_ + (xx % WS_);
            bfv8 vd = *(const bfv8*)(sC + pixl * 136 + chg * 8);
            *(bfv8*)(Q + ((((size_t)b * HEADS_ + h) * NWIN_ + wdw) * WSQ_ + j49) * DH_ + d) = vd;
        }
    }
}

// ---------------------------------------------------------------------------
// Kernel 3: windowed attention via MFMA. One block (4 waves) per (b,h,window).
// Single staging barrier; V^T staged with vector LDS writes (conflict-free);
// bias as MFMA C-init; Q pre-scaled; ps aliases qs (frag preload + barrier).
// ---------------------------------------------------------------------------
__global__ __launch_bounds__(256) void attn_mfma(
    const bf16* __restrict__ Q, const bf16* __restrict__ Kt,
    const bf16* __restrict__ V, const float* __restrict__ biasf,
    bf16* __restrict__ O) {
    __shared__ __align__(16) bf16 qs[64 * 72];   // aliased by ps after barrier 2
    __shared__ __align__(16) bf16 ks[64 * 72];
    __shared__ __align__(16) bf16 vt[64 * 72];   // V^T: [d][j]
    bf16* ps = qs;
    int tid = threadIdx.x;
    int w = blockIdx.x & 63;
    int h = (blockIdx.x >> 6) & 7;
    int b = blockIdx.x >> 9;
    size_t base = (((size_t)b * HEADS_ + h) * NWIN_ + w) * (WSQ_ * DH_);

    // ---- staging (one phase, one barrier) ----
    {
        bfv8 z = {};
        // Q/K rows [j][d], rows >=49 zeroed
#pragma unroll
        for (int it = 0; it < 2; ++it) {
            int c = it * 256 + tid;
            int row = c >> 3, col = (c & 7) * 8;
            bfv8 vq = z, vk = z;
            if (c < 392) {
                vq = *(const bfv8*)(Q + base + c * 8);
                vk = *(const bfv8*)(Kt + base + c * 8);
            }
            *(bfv8*)(qs + row * 72 + col) = vq;
            *(bfv8*)(ks + row * 72 + col) = vk;
        }
        // V^T: thread = (d, j-block). 8 coalesced scalar loads -> 1 bfv8 write.
#pragma unroll
        for (int it = 0; it < 2; ++it) {
            int idx = it * 256 + tid;
            int d = idx & 63, j8 = idx >> 6;     // j8 wave-uniform
            bf16 val[8];
            if (j8 < 6) {
#pragma unroll
                for (int u = 0; u < 8; ++u)
                    val[u] = V[base + (j8 * 8 + u) * 64 + d];
            } else {
#pragma unroll
                for (int u = 0; u < 8; ++u) {
                    int j = j8 * 8 + u;
                    val[u] = (j < WSQ_) ? V[base + j * 64 + d]
                                        : __float2bfloat16(0.f);
                }
            }
            *(bfv8*)(vt + d * 72 + j8 * 8) = *(const bfv8*)val;
        }
    }
    __syncthreads();

    int lane = tid & 63, wv = tid >> 6;
    int band = wv * 16;
    int col16 = lane & 15, quad = lane >> 4;

    // preload all Q/K fragments, then free qs/ks for ps aliasing
    bfv8 aq0 = *(const bfv8*)(qs + (band + col16) * 72 + quad * 8);
    bfv8 aq1 = *(const bfv8*)(qs + (band + col16) * 72 + 32 + quad * 8);
    bfv8 bk[4][2];
#pragma unroll
    for (int nt = 0; nt < 4; ++nt) {
        bk[nt][0] = *(const bfv8*)(ks + (nt * 16 + col16) * 72 + quad * 8);
        bk[nt][1] = *(const bfv8*)(ks + (nt * 16 + col16) * 72 + 32 + quad * 8);
    }
    __syncthreads();   // qs/ks dead; ps (== qs) may be written

    // S = (Q/8) K^T + bias  (bias as C-init; pad cols pre-set to -1e30)
    const float* bp = biasf + (((size_t)h * 4 + wv) * 64 + lane) * 16;
    f32x4 sacc[4];
#pragma unroll
    for (int nt = 0; nt < 4; ++nt) {
        sacc[nt] = *(const f32x4*)(bp + nt * 4);
        sacc[nt] = __builtin_amdgcn_mfma_f32_16x16x32_bf16(aq0, bk[nt][0], sacc[nt], 0, 0, 0);
        sacc[nt] = __builtin_amdgcn_mfma_f32_16x16x32_bf16(aq1, bk[nt][1], sacc[nt], 0, 0, 0);
    }
    // in-register softmax (width-16 row reductions)
    float p[4][4];
    float inv[4];
#pragma unroll
    for (int r = 0; r < 4; ++r) {
        float s0 = sacc[0][r], s1 = sacc[1][r], s2 = sacc[2][r], s3 = sacc[3][r];
        float mx = fmaxf(fmaxf(s0, s1), fmaxf(s2, s3));
        mx = fmaxf(mx, __shfl_xor(mx, 1, 16));
        mx = fmaxf(mx, __shfl_xor(mx, 2, 16));
        mx = fmaxf(mx, __shfl_xor(mx, 4, 16));
        mx = fmaxf(mx, __shfl_xor(mx, 8, 16));
        float e0 = __expf(s0 - mx), e1 = __expf(s1 - mx);
        float e2 = __expf(s2 - mx), e3 = __expf(s3 - mx);
        float sm = e0 + e1 + e2 + e3;
        sm += __shfl_xor(sm, 1, 16);
        sm += __shfl_xor(sm, 2, 16);
        sm += __shfl_xor(sm, 4, 16);
        sm += __shfl_xor(sm, 8, 16);
        p[0][r] = e0; p[1][r] = e1; p[2][r] = e2; p[3][r] = e3;
        inv[r] = 1.f / sm;
    }
    // P -> LDS (C-layout -> A-operand layout; own rows only, no barrier)
#pragma unroll
    for (int nt = 0; nt < 4; ++nt)
#pragma unroll
        for (int r = 0; r < 4; ++r)
            ps[(band + quad * 4 + r) * 72 + nt * 16 + col16] = __float2bfloat16(p[nt][r]);
    // O = P V^T
    f32x4 oacc[4] = {};
    bfv8 ap0 = *(const bfv8*)(ps + (band + col16) * 72 + quad * 8);
    bfv8 ap1 = *(const bfv8*)(ps + (band + col16) * 72 + 32 + quad * 8);
#pragma unroll
    for (int nt = 0; nt < 4; ++nt) {
        bfv8 bv0 = *(const bfv8*)(vt + (nt * 16 + col16) * 72 + quad * 8);
        bfv8 bv1 = *(const bfv8*)(vt + (nt * 16 + col16) * 72 + 32 + quad * 8);
        oacc[nt] = __builtin_amdgcn_mfma_f32_16x16x32_bf16(ap0, bv0, oacc[nt], 0, 0, 0);
        oacc[nt] = __builtin_amdgcn_mfma_f32_16x16x32_bf16(ap1, bv1, oacc[nt], 0, 0, 0);
    }
    int wy = w >> 3, wx = w & 7;
#pragma unroll
    for (int r = 0; r < 4; ++r) {
        int i = band + quad * 4 + r;
        if (i < WSQ_) {
            int py = wy * WS_ + i / WS_, px = wx * WS_ + i % WS_;
            size_t ob = ((size_t)b * NPIX_ + py * HW_ + px) * INNER_ + h * DH_;
            float sc = inv[r];
#pragma unroll
            for (int nt = 0; nt < 4; ++nt)
                O[ob + nt * 16 + col16] = __float2bfloat16(oacc[nt][r] * sc);
        }
    }
}

// ---------------------------------------------------------------------------
// Kernel 4: output pointwise GEMM via MFMA + bias (fp32 out).
// ---------------------------------------------------------------------------
__global__ __launch_bounds__(256) void gemm_out_mfma(
    const bf16* __restrict__ W, const bf16* __restrict__ O,
    const float* __restrict__ bias, float* __restrict__ out) {
    __shared__ __align__(16) bf16 sA[128 * 32];
    __shared__ __align__(16) bf16 sB[128 * 32];
    int tid = threadIdx.x;
    int c0 = blockIdx.x * 128;
    int p0 = blockIdx.y * 128;
    int b  = blockIdx.z;

    int row0 = tid >> 2;
    int kc   = (tid & 3) * 8;
    int pB0 = p0 + row0;       if (pB0 > NPIX_ - 1) pB0 = NPIX_ - 1;
    int pB1 = p0 + row0 + 64;  if (pB1 > NPIX_ - 1) pB1 = NPIX_ - 1;
    const bf16* gA0 = W + (size_t)(c0 + row0) * 512 + kc;
    const bf16* gA1 = W + (size_t)(c0 + row0 + 64) * 512 + kc;
    const bf16* gB0 = O + ((size_t)b * NPIX_ + pB0) * 512 + kc;
    const bf16* gB1 = O + ((size_t)b * NPIX_ + pB1) * 512 + kc;
    char* lA = (char*)sA + tid * 16;
    char* lB = (char*)sB + tid * 16;

    int lane = tid & 63, wv = tid >> 6;
    int wm = (wv >> 1) * 64;
    int wn = (wv & 1) * 64;
    int col16 = lane & 15, quad = lane >> 4;

    f32x4 acc[4][4] = {};
    for (int k0 = 0; k0 < 512; k0 += 32) {
        async16(gA0, lA);
        async16(gA1, lA + 4096);
        async16(gB0, lB);
        async16(gB1, lB + 4096);
        gA0 += 32; gA1 += 32; gB0 += 32; gB1 += 32;
        __syncthreads();
        bfv8 af[4], bfr[4];
#pragma unroll
        for (int mt = 0; mt < 4; ++mt)
            af[mt] = *(const bfv8*)(sA + (wm + mt * 16 + col16) * 32 + quad * 8);
#pragma unroll
        for (int nt = 0; nt < 4; ++nt)
            bfr[nt] = *(const bfv8*)(sB + (wn + nt * 16 + col16) * 32 + quad * 8);
#pragma unroll
        for (int mt = 0; mt < 4; ++mt)
#pragma unroll
            for (int nt = 0; nt < 4; ++nt)
                acc[mt][nt] = __builtin_amdgcn_mfma_f32_16x16x32_bf16(
                    af[mt], bfr[nt], acc[mt][nt], 0, 0, 0);
        __syncthreads();
    }
#pragma unroll
    for (int mt = 0; mt < 4; ++mt) {
#pragma unroll
        for (int r = 0; r < 4; ++r) {
            int ch = c0 + wm + mt * 16 + quad * 4 + r;
            float bc = bias[ch];
#pragma unroll
            for (int nt = 0; nt < 4; ++nt) {
                int p = p0 + wn + nt * 16 + col16;
                if (p < NPIX_)
                    out[((size_t)b * C_ + ch) * NPIX_ + p] = acc[mt][nt][r] + bc;
            }
        }
    }
}

// ---------------------------------------------------------------------------
extern "C" void kernel_launch(void* const* d_in, const int* in_sizes, int n_in,
                              void* d_out, int out_size, void* d_ws, size_t ws_size,
                              hipStream_t stream) {
    (void)in_sizes; (void)n_in; (void)out_size; (void)ws_size;
    const float* x     = (const float*)d_in[0];
    const float* pos   = (const float*)d_in[19];
    const float* out_w = (const float*)d_in[20];
    const float* out_b = (const float*)d_in[21];

    size_t tElems = (size_t)B_ * NPIX_ * C_;        // 12.845M
    size_t qElems = (size_t)B_ * INNER_ * NPIX_;    // 25.69M
    bf16* tq = (bf16*)d_ws;                         // t's: [3][B][pix][256]
    bf16* q  = tq + 3 * tElems;                     // qkv: [3][B][h][w][49][64]
    bf16* o  = tq;                                  // aliases tq+tk (dead by attn)
    float* wf = (float*)(q + 3 * qElems);           // [3][256][12] fp32
    bf16* wq = (bf16*)(wf + 3 * 256 * 12);          // [4][512*256] bf16 weights
    bf16* wo = wq + 3 * (INNER_ * C_);
    float* biasf = (float*)(wo + C_ * INNER_);      // [8][4][64][16] fp32

    dim3 blk(256);
    dim3 gDw(HW_, 4, B_);                           // 56 x 4 x 16
    dim3 gQkv(INNER_ / 128, 25, 3 * B_);            // z = p*16 + b
    dim3 gOut(C_ / 128, 25, B_);

    setup_kernel<<<2059, blk, 0, stream>>>(
        (const float*)d_in[6], (const float*)d_in[12], (const float*)d_in[18],
        out_w, wq,
        (const float*)d_in[1],  (const float*)d_in[2],  (const float*)d_in[3],
        (const float*)d_in[4],  (const float*)d_in[5],
        (const float*)d_in[7],  (const float*)d_in[8],  (const float*)d_in[9],
        (const float*)d_in[10], (const float*)d_in[11],
        (const float*)d_in[13], (const float*)d_in[14], (const float*)d_in[15],
        (const float*)d_in[16], (const float*)d_in[17], wf,
        pos, biasf);

    dwbn3_kernel<<<gDw, blk, 0, stream>>>(x, wf, tq, tq + tElems, tq + 2 * tElems);
    gemm_qkv_mfma<<<gQkv, blk, 0, stream>>>(wq, tq, q);
    attn_mfma<<<B_ * HEADS_ * NWIN_, blk, 0, stream>>>(
        q, q + qElems, q + 2 * qElems, biasf, o);
    gemm_out_mfma<<<gOut, blk, 0, stream>>>(wo, o, out_b, (float*)d_out);
}